// Round 13
// baseline (879.467 us; speedup 1.0000x reference)
//
#include <hip/hip_runtime.h>

#define NEG_SLOPE 0.2f

typedef __attribute__((ext_vector_type(4))) float floatx4;
typedef __attribute__((ext_vector_type(8))) short shortx8;

__device__ __forceinline__ unsigned short f2bf(float f) {
  union { float f; unsigned int u; } v;
  v.f = f;
  unsigned int r = (v.u + 0x7FFFu + ((v.u >> 16) & 1u)) >> 16;
  return (unsigned short)r;
}
__device__ __forceinline__ float bf2f(unsigned short u) {
  union { unsigned int u; float f; } v;
  v.u = (unsigned int)u << 16;
  return v.f;
}
__device__ __forceinline__ void store_out(float* p, float v) { *p = v; }
__device__ __forceinline__ void store_out(unsigned short* p, float v) { *p = f2bf(v); }

// async global->LDS, 16B per lane, LDS dest = wave-uniform base + lane*16
__device__ __forceinline__ void gload_lds16(const unsigned short* g, unsigned short* l) {
  __builtin_amdgcn_global_load_lds(
      (const __attribute__((address_space(1))) void*)(g),
      (__attribute__((address_space(3))) void*)(l), 16, 0, 0);
}

// ---------------- edge index width detection (int32 vs int64) ----------------
__device__ __forceinline__ int load_edge(const void* ei, long idx, int is64) {
  if (is64) return (int)((const long long*)ei)[idx];
  return ((const int*)ei)[idx];
}

__global__ void detect64_kernel(const unsigned int* __restrict__ p, int* __restrict__ flag) {
  int is64 = 1;
  for (int i = 0; i < 32; ++i)
    if (p[2 * i + 1] != 0u) is64 = 0;
  *flag = is64;
}

// ---------------- CSR build ----------------
__global__ void init_cnt_kernel(int* __restrict__ cnt, int n) {
  int i = blockIdx.x * blockDim.x + threadIdx.x;
  if (i < n) cnt[i] = 1;  // self-loop
}

__global__ void count_kernel(const void* __restrict__ ei, const int* __restrict__ flag, int E,
                             int* __restrict__ cnt) {
  int e = blockIdx.x * blockDim.x + threadIdx.x;
  if (e >= E) return;
  int is64 = *flag;
  int d = load_edge(ei, (long)E + e, is64);
  atomicAdd(&cnt[d], 1);
}

__global__ __launch_bounds__(1024) void scan_kernel(const int* __restrict__ cnt,
                                                    int* __restrict__ offs, int n) {
  __shared__ int partial[1024];
  int t = threadIdx.x;
  int per = (n + 1023) / 1024;
  int beg = t * per;
  int end = min(beg + per, n);
  int sum = 0;
  for (int i = beg; i < end; ++i) sum += cnt[i];
  partial[t] = sum;
  __syncthreads();
  for (int d = 1; d < 1024; d <<= 1) {
    int v = (t >= d) ? partial[t - d] : 0;
    __syncthreads();
    partial[t] += v;
    __syncthreads();
  }
  int excl = (t == 0) ? 0 : partial[t - 1];
  for (int i = beg; i < end; ++i) { offs[i] = excl; excl += cnt[i]; }
  if (t == 1023) offs[n] = partial[1023];
}

__global__ void init_self_kernel(const int* __restrict__ offs, int* __restrict__ srcs,
                                 int* __restrict__ fill, int n) {
  int i = blockIdx.x * blockDim.x + threadIdx.x;
  if (i < n) { srcs[offs[i]] = i; fill[i] = 1; }
}

__global__ void scatter_kernel(const void* __restrict__ ei, const int* __restrict__ flag, int E,
                               const int* __restrict__ offs, int* __restrict__ fill,
                               int* __restrict__ srcs) {
  int e = blockIdx.x * blockDim.x + threadIdx.x;
  if (e >= E) return;
  int is64 = *flag;
  int s = load_edge(ei, e, is64);
  int d = load_edge(ei, (long)E + e, is64);
  int pos = offs[d] + atomicAdd(&fill[d], 1);
  srcs[pos] = s;
}

// ---------------- packers: emit tile-panel-major layout [rt][kc][r128][8] ----------------
// (R5 win: +76% on GEMM. Element (row,k) lives at P[row>>7][k>>3][row&127][k&7],
// so each GEMM K-iter stages contiguous panel-slabs.)

// x f32 [M][K] -> packed bf16 [Mpad/128][Kpad/8][128][8]; rows>=M zero-filled.
__global__ __launch_bounds__(256) void pack_a_kernel(const float* __restrict__ in,
                                                     unsigned short* __restrict__ out, int M,
                                                     int K, int Kpad) {
  int rt = blockIdx.x;
  int r = threadIdx.x & 127;
  int kq = threadIdx.x >> 7;  // 0..1
  int row = rt * 128 + r;
  int nkc = Kpad >> 3;
  unsigned short* obase = out + (long)rt * Kpad * 128 + r * 8;
  const float* irow = in + (long)row * K;
  for (int kc = kq + (int)blockIdx.y * 2; kc < nkc; kc += (int)gridDim.y * 2) {
    int k = kc << 3;
    shortx8 o;
    if (row < M && k + 8 <= K && (K & 3) == 0) {
      float4 v0 = *(const float4*)(irow + k);
      float4 v1 = *(const float4*)(irow + k + 4);
      o[0] = (short)f2bf(v0.x); o[1] = (short)f2bf(v0.y);
      o[2] = (short)f2bf(v0.z); o[3] = (short)f2bf(v0.w);
      o[4] = (short)f2bf(v1.x); o[5] = (short)f2bf(v1.y);
      o[6] = (short)f2bf(v1.z); o[7] = (short)f2bf(v1.w);
    } else {
#pragma unroll
      for (int i = 0; i < 8; ++i) {
        int kk = k + i;
        float v = (row < M && kk < K) ? irow[kk] : 0.f;
        o[i] = (short)f2bf(v);
      }
    }
    *(shortx8*)(obase + (long)kc * 1024) = o;
  }
}

// W f32 [K][N] -> packed bf16 [N/128][Kpad/8][128][8] (transpose + pack).
__global__ __launch_bounds__(256) void transpose_pack_kernel(const float* __restrict__ in,
                                                             unsigned short* __restrict__ out,
                                                             int K, int N, int Kpad) {
  __shared__ float tile[32][33];
  int kb = blockIdx.x * 32;
  int nb = blockIdx.y * 32;
  int tx = threadIdx.x & 31;
  int ty = threadIdx.x >> 5;
#pragma unroll
  for (int i = 0; i < 32; i += 8) {
    int k = kb + ty + i;
    tile[ty + i][tx] = (k < K) ? in[(long)k * N + nb + tx] : 0.f;
  }
  __syncthreads();
  if (threadIdx.x < 128) {
    int nl = threadIdx.x & 31;
    int nn = nb + nl;
    int kc4 = threadIdx.x >> 5;  // 0..3
    int k0 = kc4 * 8;
    shortx8 o;
#pragma unroll
    for (int j = 0; j < 8; ++j) o[j] = (short)f2bf(tile[k0 + j][nl]);
    int kc = (kb >> 3) + kc4;
    *(shortx8*)(out + (long)(nn >> 7) * Kpad * 128 + (long)kc * 1024 + (nn & 127) * 8) = o;
  }
}

// ---------------- bf16 MFMA GEMM — 256x256 tile, packed operands, dbuf DMA pipeline ----------------
// C[M,N] = A[M,K] * Bt[N,K]^T, both operands packed [*/128][K/8][128][8].
// R12 diagnosis: 128^2 GEMM at 567 TF == the measured 2-phase structural ceiling
// (m233: ~607 TF; stage+vmcnt+barrier = ~72% of each iter). Escape without
// changing the verified sync: 256^2 tile (m230/m248v2: same 2-phase sync at
// 256^2 = 655-682 TF) — 2x MFMA per barrier pair, half the staged bytes/FLOP.
// This kernel = R4's HW-verified 256^2/512-thread/2x4-wave structure + R5's
// packed staging. Per K-iter (BK=32) each operand stages TWO contiguous 8KB
// panel-slabs (packed panels are 128 rows): 4 DMA issues/thread-block-iter.
// LDS = [buf2][half2][kc4][row128][8] per operand (64KB total, 2 blocks/CU).
// Sync per K-iter (R4/R5-verified): issue next tile's 4 DMA loads -> s_waitcnt
// vmcnt(4) (next tile flies across the bare s_barrier; never vmcnt(0) mid-loop)
// -> barrier -> frags + 32 MFMA/wave -> bare barrier (WAR guard).
//   0x0F74 = vmcnt(4)   0x0F70 = vmcnt(0) (last iter).
// Frag reads conflict-free (same quad*1024 + row*8 pattern as the verified
// 128^2 kernel; lanes 0-15 read 256B contiguous).
// Requires K%32==0, N%256==0, A packed to gridDim.y*256 rows.
template <typename OT>
__global__ __launch_bounds__(512) void mfma_gemm_kernel(const unsigned short* __restrict__ A,
                                                        const unsigned short* __restrict__ Bt,
                                                        OT* __restrict__ C, int M, int N, int K) {
  __shared__ unsigned short As[2][8192];
  __shared__ unsigned short Bs[2][8192];

  int tid = threadIdx.x;
  int lane = tid & 63;
  int w = tid >> 6;             // 0..7
  int wm = w >> 2, wn = w & 3;  // 2 x 4 wave grid
  int bn = blockIdx.x * 256;    // N-tile fastest
  int bm = blockIdx.y * 256;
  int quad = lane >> 4, l16 = lane & 15;

  // packed staging: panels p0=bm>>7, p0+1 (A) and q0=bn>>7, q0+1 (B);
  // per iter k each panel contributes the contiguous 4096-short slab at k*4096.
  const unsigned short* pA0 = A + (long)(bm >> 7) * K * 128 + tid * 8;
  const unsigned short* pA1 = pA0 + (long)K * 128;
  const unsigned short* pB0 = Bt + (long)(bn >> 7) * K * 128 + tid * 8;
  const unsigned short* pB1 = pB0 + (long)K * 128;
  // wave-uniform LDS bases: dest = base + lane*16B; second panel at +4096
  unsigned short* la = &As[0][0] + w * 512;
  unsigned short* lb = &Bs[0][0] + w * 512;

  floatx4 acc[8][4];
#pragma unroll
  for (int i = 0; i < 8; ++i)
#pragma unroll
    for (int j = 0; j < 4; ++j) acc[i][j] = (floatx4){0.f, 0.f, 0.f, 0.f};

  // prologue: stage tile 0 into buffer 0
  gload_lds16(pA0, la);
  gload_lds16(pA1, la + 4096);
  gload_lds16(pB0, lb);
  gload_lds16(pB1, lb + 4096);

  int nk = K >> 5;
  for (int k = 0; k < nk; ++k) {
    int cur = k & 1;
    if (k + 1 < nk) {
      // issue next tile's 4 DMA loads — they fly across the barrier
      long o = (long)(k + 1) * 4096;
      unsigned short* da = la + (cur ^ 1) * 8192;
      unsigned short* db = lb + (cur ^ 1) * 8192;
      gload_lds16(pA0 + o, da);
      gload_lds16(pA1 + o, da + 4096);
      gload_lds16(pB0 + o, db);
      gload_lds16(pB1 + o, db + 4096);
      __builtin_amdgcn_s_waitcnt(0x0F74);  // vmcnt(4): tile k done, k+1 in flight
    } else {
      __builtin_amdgcn_s_waitcnt(0x0F70);  // vmcnt(0): drain final tile
    }
    __builtin_amdgcn_s_barrier();  // bare barrier: in-flight DMA untouched

    shortx8 b[4];
#pragma unroll
    for (int j = 0; j < 4; ++j) {
      int c = wn * 64 + j * 16 + l16;
      b[j] = *(const shortx8*)(&Bs[cur][(c >> 7) * 4096 + quad * 1024 + (c & 127) * 8]);
    }
#pragma unroll
    for (int i = 0; i < 8; ++i) {
      int r = i * 16 + l16;  // row within this wave's half (half = wm)
      shortx8 a = *(const shortx8*)(&As[cur][wm * 4096 + quad * 1024 + r * 8]);
#pragma unroll
      for (int j = 0; j < 4; ++j)
        acc[i][j] = __builtin_amdgcn_mfma_f32_16x16x32_bf16(a, b[j], acc[i][j], 0, 0, 0);
    }

    // WAR guard: next iter's stage overwrites buf[cur^1]; all reads of that
    // buffer retired before this barrier (MFMA data-dep drained lgkm).
    __builtin_amdgcn_s_barrier();
  }

  // epilogue: C/D layout col=lane&15, row=quad*4+reg
  int orow0 = bm + wm * 128 + quad * 4;
  int ocol0 = bn + wn * 64 + l16;
#pragma unroll
  for (int i = 0; i < 8; ++i)
#pragma unroll
    for (int j = 0; j < 4; ++j)
#pragma unroll
      for (int r2 = 0; r2 < 4; ++r2) {
        int rr = orow0 + i * 16 + r2;
        if (rr < M) store_out(&C[(long)rr * N + ocol0 + j * 16], acc[i][j][r2]);
      }
}

// ---------------- attention coefficients from bf16 h ----------------
__global__ __launch_bounds__(256) void att_coef_kernel(const unsigned short* __restrict__ h,
                                                       const float* __restrict__ att_s,
                                                       const float* __restrict__ att_d,
                                                       float* __restrict__ a_s,
                                                       float* __restrict__ a_d, int n, int H,
                                                       int C) {
  int wave = (int)((blockIdx.x * blockDim.x + threadIdx.x) >> 6);
  int lane = threadIdx.x & 63;
  if (wave >= n) return;
  const unsigned short* row = h + (long)wave * H * C;
  for (int hh = 0; hh < H; ++hh) {
    float s = 0.f, d = 0.f;
    for (int c = lane; c < C; c += 64) {
      float v = bf2f(row[hh * C + c]);
      s += v * att_s[hh * C + c];
      d += v * att_d[hh * C + c];
    }
#pragma unroll
    for (int o = 32; o > 0; o >>= 1) {
      s += __shfl_down(s, o, 64);
      d += __shfl_down(d, o, 64);
    }
    if (lane == 0) {
      a_s[(long)wave * H + hh] = s;
      a_d[(long)wave * H + hh] = d;
    }
  }
}

// ---------------- per-(dst,head) segment softmax over CSR ----------------
__global__ void edge_softmax_kernel(const float* __restrict__ a_src,
                                    const float* __restrict__ a_dst,
                                    const int* __restrict__ offs, const int* __restrict__ srcs,
                                    float* __restrict__ alpha, int n, int H) {
  int idx = blockIdx.x * blockDim.x + threadIdx.x;
  if (idx >= n * H) return;
  int dstn = idx / H;
  int hh = idx - dstn * H;
  int beg = offs[dstn], end = offs[dstn + 1];
  float ad = a_dst[idx];
  float m = -1e30f;
  for (int j = beg; j < end; ++j) {
    float e = a_src[srcs[j] * H + hh] + ad;
    e = e > 0.f ? e : NEG_SLOPE * e;
    m = fmaxf(m, e);
  }
  float ssum = 0.f;
  for (int j = beg; j < end; ++j) {
    float e = a_src[srcs[j] * H + hh] + ad;
    e = e > 0.f ? e : NEG_SLOPE * e;
    float ex = __expf(e - m);
    alpha[(long)j * H + hh] = ex;
    ssum += ex;
  }
  float inv = 1.f / ssum;
  for (int j = beg; j < end; ++j) alpha[(long)j * H + hh] *= inv;
}

// ---------------- layer-1 aggregation: bf16 h -> packed bf16 xb2 (R5/R10-proven) ----------------
// One dst per block: the WHOLE block walks one edge list in lockstep; lanes
// read consecutive fids of the same src row -> fully coalesced reads (the 563MB
// side). Packed write is 16B-strided (write amplification) but writes are only
// ~52MB — R11 proved trading read coalescing for write coalescing loses 64us.
__global__ __launch_bounds__(320) void aggregate1_kernel(const unsigned short* __restrict__ h,
                                                         const float* __restrict__ alpha,
                                                         const int* __restrict__ offs,
                                                         const int* __restrict__ srcs,
                                                         const float* __restrict__ bias,
                                                         unsigned short* __restrict__ out, int H,
                                                         int C, int HC) {
  int dstn = blockIdx.x;
  int t = threadIdx.x;
  int beg = offs[dstn], end = offs[dstn + 1];
  int nf8 = HC >> 3;
  for (int fid = t; fid < nf8; fid += blockDim.x) {
    int hh = (fid << 3) / C;
    float acc[8];
#pragma unroll
    for (int i = 0; i < 8; ++i) acc[i] = 0.f;
    for (int j = beg; j < end; ++j) {
      int s = srcs[j];
      float al = alpha[(long)j * H + hh];
      shortx8 r = ((const shortx8*)(h + (long)s * HC))[fid];
#pragma unroll
      for (int i = 0; i < 8; ++i) acc[i] = fmaf(al, bf2f((unsigned short)r[i]), acc[i]);
    }
    shortx8 o;
#pragma unroll
    for (int i = 0; i < 8; ++i) {
      float bb = bias[(fid << 3) + i];
      o[i] = (short)f2bf(fmaxf(acc[i] + bb, 0.f));
    }
    // packed layout: (row=dstn, kc=fid) -> [dstn>>7][fid][dstn&127][8]
    *(shortx8*)(out + (long)(dstn >> 7) * HC * 128 + (long)fid * 1024 + (dstn & 127) * 8) = o;
  }
}

// ---------------- layer-2 aggregation with head-mean: vectorized, NO atomics (R12-proven) ----------------
__global__ __launch_bounds__(256) void aggregate2_kernel(const unsigned short* __restrict__ h,
                                                         const float* __restrict__ alpha,
                                                         const int* __restrict__ offs,
                                                         const int* __restrict__ srcs,
                                                         const float* __restrict__ bias,
                                                         float* __restrict__ out, int H, int C) {
  __shared__ float smem[16 * 256];  // nHgrp x C, C<=256
  int dstn = blockIdx.x;
  int t = threadIdx.x;
  int HC = H * C;
  int nc8 = C >> 3;                 // 16 for C=128
  int c8 = t & (nc8 - 1);
  int hgrp = t >> __builtin_ctz(nc8);  // 0..nHgrp-1
  int nHgrp = 256 >> __builtin_ctz(nc8);
  int beg = offs[dstn], end = offs[dstn + 1];

  float acc[2][8];
#pragma unroll
  for (int hi = 0; hi < 2; ++hi)
#pragma unroll
    for (int i = 0; i < 8; ++i) acc[hi][i] = 0.f;

  for (int j = beg; j < end; ++j) {
    int s = srcs[j];
    const unsigned short* row = h + (long)s * HC;
    const float* al = alpha + (long)j * H;
#pragma unroll
    for (int hi = 0; hi < 2; ++hi) {
      int hh = hgrp + hi * nHgrp;
      if (hh < H) {
        float a = al[hh];
        shortx8 r = *(const shortx8*)(row + hh * C + c8 * 8);
#pragma unroll
        for (int i = 0; i < 8; ++i) acc[hi][i] = fmaf(a, bf2f((unsigned short)r[i]), acc[hi][i]);
      }
    }
  }
  // fold this thread's two head-slices, park in smem[hgrp][c]
#pragma unroll
  for (int i = 0; i < 8; ++i) smem[hgrp * C + c8 * 8 + i] = acc[0][i] + acc[1][i];
  __syncthreads();
  float invH = 1.f / (float)H;
  for (int c = t; c < C; c += 256) {
    float s = 0.f;
    for (int g = 0; g < nHgrp; ++g) s += smem[g * C + c];
    float v = s * invH + bias[c];
    out[(long)dstn * C + c] = v > 0.f ? v : 0.f;
  }
}

// ---------------- host ----------------
static inline size_t align256(size_t x) { return (x + 255) & ~(size_t)255; }

extern "C" void kernel_launch(void* const* d_in, const int* in_sizes, int n_in, void* d_out,
                              int out_size, void* d_ws, size_t ws_size, hipStream_t stream) {
  const float* x        = (const float*)d_in[0];
  const void*  ei       = d_in[1];
  const float* W1       = (const float*)d_in[2];
  const float* att_src1 = (const float*)d_in[3];
  const float* att_dst1 = (const float*)d_in[4];
  const float* b1       = (const float*)d_in[5];
  const float* W2       = (const float*)d_in[6];
  const float* att_src2 = (const float*)d_in[7];
  const float* att_dst2 = (const float*)d_in[8];
  const float* b2       = (const float*)d_in[9];
  float* out = (float*)d_out;

  const int C2  = in_sizes[9];       // 128
  const int H   = in_sizes[7] / C2;  // 20
  const int HC1 = in_sizes[5];       // 2560
  const int C1  = HC1 / H;           // 128
  const int G   = in_sizes[2] / HC1; // 2000
  const int Nn  = in_sizes[0] / G;   // 10000
  const int E   = in_sizes[1] / 2;   // 100000
  const int HC2 = H * C2;            // 2560
  const int Et  = E + Nn;
  const int Mpad = ((Nn + 255) / 256) * 256;   // 256-tile M padding (10240)
  const int K1pad = ((G + 31) / 32) * 32;      // 2048

  // workspace layout — R5-exact structure, Mpad now 256-aligned
  char* p = (char*)d_ws;
  size_t off = 0;
  unsigned short* hb  = (unsigned short*)(p + off); off = align256(off + (size_t)Mpad * (HC1 > HC2 ? HC1 : HC2) * 2);
  unsigned short* xb  = (unsigned short*)(p + off); off = align256(off + (size_t)Mpad * K1pad * 2);
  unsigned short* xb2 = (unsigned short*)(p + off); off = align256(off + (size_t)Mpad * HC1 * 2);
  unsigned short* W1t = (unsigned short*)(p + off); off = align256(off + (size_t)HC1 * K1pad * 2);
  unsigned short* W2t = (unsigned short*)(p + off); off = align256(off + (size_t)HC2 * HC1 * 2);
  float* a_s   = (float*)(p + off); off = align256(off + (size_t)Nn * H * 4);
  float* a_d   = (float*)(p + off); off = align256(off + (size_t)Nn * H * 4);
  float* alpha = (float*)(p + off); off = align256(off + (size_t)Et * H * 4);
  int* cnt     = (int*)(p + off); off = align256(off + (size_t)Nn * 4);
  int* offs    = (int*)(p + off); off = align256(off + (size_t)(Nn + 1) * 4);
  int* fill    = (int*)(p + off); off = align256(off + (size_t)Nn * 4);
  int* srcs    = (int*)(p + off); off = align256(off + (size_t)Et * 4);
  int* flag64  = (int*)(p + off); off = align256(off + 16);
  (void)ws_size; (void)n_in; (void)out_size;

  const int TB = 256;
  // CSR build
  detect64_kernel<<<1, 1, 0, stream>>>((const unsigned int*)ei, flag64);
  init_cnt_kernel<<<(Nn + TB - 1) / TB, TB, 0, stream>>>(cnt, Nn);
  count_kernel<<<(E + TB - 1) / TB, TB, 0, stream>>>(ei, flag64, E, cnt);
  scan_kernel<<<1, 1024, 0, stream>>>(cnt, offs, Nn);
  init_self_kernel<<<(Nn + TB - 1) / TB, TB, 0, stream>>>(offs, srcs, fill, Nn);
  scatter_kernel<<<(E + TB - 1) / TB, TB, 0, stream>>>(ei, flag64, E, offs, fill, srcs);

  // packed-layout operand prep
  {
    dim3 ga(Mpad / 128, 8);
    pack_a_kernel<<<ga, 256, 0, stream>>>(x, xb, Nn, G, K1pad);
    dim3 g1(K1pad / 32, HC1 / 32);
    transpose_pack_kernel<<<g1, 256, 0, stream>>>(W1, W1t, G, HC1, K1pad);
    dim3 g2(HC1 / 32, HC2 / 32);
    transpose_pack_kernel<<<g2, 256, 0, stream>>>(W2, W2t, HC1, HC2, HC1);
  }

  // layer 1
  {
    dim3 grid(HC1 / 256, Mpad / 256);  // N-tile fastest
    mfma_gemm_kernel<unsigned short><<<grid, 512, 0, stream>>>(xb, W1t, hb, Nn, HC1, K1pad);
  }
  att_coef_kernel<<<(Nn + 3) / 4, 256, 0, stream>>>(hb, att_src1, att_dst1, a_s, a_d, Nn, H, C1);
  edge_softmax_kernel<<<(Nn * H + TB - 1) / TB, TB, 0, stream>>>(a_s, a_d, offs, srcs, alpha, Nn, H);
  aggregate1_kernel<<<Nn, 320, 0, stream>>>(hb, alpha, offs, srcs, b1, xb2, H, C1, HC1);

  // layer 2
  {
    dim3 grid(HC2 / 256, Mpad / 256);
    mfma_gemm_kernel<unsigned short><<<grid, 512, 0, stream>>>(xb2, W2t, hb, Nn, HC2, HC1);
  }
  att_coef_kernel<<<(Nn + 3) / 4, 256, 0, stream>>>(hb, att_src2, att_dst2, a_s, a_d, Nn, H, C2);
  edge_softmax_kernel<<<(Nn * H + TB - 1) / TB, TB, 0, stream>>>(a_s, a_d, offs, srcs, alpha, Nn, H);
  aggregate2_kernel<<<Nn, 256, 0, stream>>>(hb, alpha, offs, srcs, b2, out, H, C2);
}

// Round 14
// 860.913 us; speedup vs baseline: 1.0216x; 1.0216x over previous
//
#include <hip/hip_runtime.h>

#define NEG_SLOPE 0.2f

typedef __attribute__((ext_vector_type(4))) float floatx4;
typedef __attribute__((ext_vector_type(8))) short shortx8;

__device__ __forceinline__ unsigned short f2bf(float f) {
  union { float f; unsigned int u; } v;
  v.f = f;
  unsigned int r = (v.u + 0x7FFFu + ((v.u >> 16) & 1u)) >> 16;
  return (unsigned short)r;
}
__device__ __forceinline__ float bf2f(unsigned short u) {
  union { unsigned int u; float f; } v;
  v.u = (unsigned int)u << 16;
  return v.f;
}
__device__ __forceinline__ void store_out(float* p, float v) { *p = v; }
__device__ __forceinline__ void store_out(unsigned short* p, float v) { *p = f2bf(v); }

// async global->LDS, 16B per lane, LDS dest = wave-uniform base + lane*16
__device__ __forceinline__ void gload_lds16(const unsigned short* g, unsigned short* l) {
  __builtin_amdgcn_global_load_lds(
      (const __attribute__((address_space(1))) void*)(g),
      (__attribute__((address_space(3))) void*)(l), 16, 0, 0);
}

// ---------------- edge index width detection (int32 vs int64) ----------------
__device__ __forceinline__ int load_edge(const void* ei, long idx, int is64) {
  if (is64) return (int)((const long long*)ei)[idx];
  return ((const int*)ei)[idx];
}

__global__ void detect64_kernel(const unsigned int* __restrict__ p, int* __restrict__ flag) {
  int is64 = 1;
  for (int i = 0; i < 32; ++i)
    if (p[2 * i + 1] != 0u) is64 = 0;
  *flag = is64;
}

// ---------------- CSR build ----------------
__global__ void init_cnt_kernel(int* __restrict__ cnt, int n) {
  int i = blockIdx.x * blockDim.x + threadIdx.x;
  if (i < n) cnt[i] = 1;  // self-loop
}

__global__ void count_kernel(const void* __restrict__ ei, const int* __restrict__ flag, int E,
                             int* __restrict__ cnt) {
  int e = blockIdx.x * blockDim.x + threadIdx.x;
  if (e >= E) return;
  int is64 = *flag;
  int d = load_edge(ei, (long)E + e, is64);
  atomicAdd(&cnt[d], 1);
}

__global__ __launch_bounds__(1024) void scan_kernel(const int* __restrict__ cnt,
                                                    int* __restrict__ offs, int n) {
  __shared__ int partial[1024];
  int t = threadIdx.x;
  int per = (n + 1023) / 1024;
  int beg = t * per;
  int end = min(beg + per, n);
  int sum = 0;
  for (int i = beg; i < end; ++i) sum += cnt[i];
  partial[t] = sum;
  __syncthreads();
  for (int d = 1; d < 1024; d <<= 1) {
    int v = (t >= d) ? partial[t - d] : 0;
    __syncthreads();
    partial[t] += v;
    __syncthreads();
  }
  int excl = (t == 0) ? 0 : partial[t - 1];
  for (int i = beg; i < end; ++i) { offs[i] = excl; excl += cnt[i]; }
  if (t == 1023) offs[n] = partial[1023];
}

__global__ void init_self_kernel(const int* __restrict__ offs, int* __restrict__ srcs,
                                 int* __restrict__ fill, int n) {
  int i = blockIdx.x * blockDim.x + threadIdx.x;
  if (i < n) { srcs[offs[i]] = i; fill[i] = 1; }
}

__global__ void scatter_kernel(const void* __restrict__ ei, const int* __restrict__ flag, int E,
                               const int* __restrict__ offs, int* __restrict__ fill,
                               int* __restrict__ srcs) {
  int e = blockIdx.x * blockDim.x + threadIdx.x;
  if (e >= E) return;
  int is64 = *flag;
  int s = load_edge(ei, e, is64);
  int d = load_edge(ei, (long)E + e, is64);
  int pos = offs[d] + atomicAdd(&fill[d], 1);
  srcs[pos] = s;
}

// ---------------- packers: emit tile-panel-major layout [rt][kc][r128][8] ----------------
// (R5 win: +76% on GEMM. Element (row,k) lives at P[row>>7][k>>3][row&127][k&7],
// so each GEMM K-iter stages one CONTIGUOUS 8KB span per operand.)

// x f32 [M][K] -> packed bf16 [Mpad/128][Kpad/8][128][8]; rows>=M zero-filled.
__global__ __launch_bounds__(256) void pack_a_kernel(const float* __restrict__ in,
                                                     unsigned short* __restrict__ out, int M,
                                                     int K, int Kpad) {
  int rt = blockIdx.x;
  int r = threadIdx.x & 127;
  int kq = threadIdx.x >> 7;  // 0..1
  int row = rt * 128 + r;
  int nkc = Kpad >> 3;
  unsigned short* obase = out + (long)rt * Kpad * 128 + r * 8;
  const float* irow = in + (long)row * K;
  for (int kc = kq + (int)blockIdx.y * 2; kc < nkc; kc += (int)gridDim.y * 2) {
    int k = kc << 3;
    shortx8 o;
    if (row < M && k + 8 <= K && (K & 3) == 0) {
      float4 v0 = *(const float4*)(irow + k);
      float4 v1 = *(const float4*)(irow + k + 4);
      o[0] = (short)f2bf(v0.x); o[1] = (short)f2bf(v0.y);
      o[2] = (short)f2bf(v0.z); o[3] = (short)f2bf(v0.w);
      o[4] = (short)f2bf(v1.x); o[5] = (short)f2bf(v1.y);
      o[6] = (short)f2bf(v1.z); o[7] = (short)f2bf(v1.w);
    } else {
#pragma unroll
      for (int i = 0; i < 8; ++i) {
        int kk = k + i;
        float v = (row < M && kk < K) ? irow[kk] : 0.f;
        o[i] = (short)f2bf(v);
      }
    }
    *(shortx8*)(obase + (long)kc * 1024) = o;
  }
}

// W f32 [K][N] -> packed bf16 [N/128][Kpad/8][128][8] (transpose + pack).
__global__ __launch_bounds__(256) void transpose_pack_kernel(const float* __restrict__ in,
                                                             unsigned short* __restrict__ out,
                                                             int K, int N, int Kpad) {
  __shared__ float tile[32][33];
  int kb = blockIdx.x * 32;
  int nb = blockIdx.y * 32;
  int tx = threadIdx.x & 31;
  int ty = threadIdx.x >> 5;
#pragma unroll
  for (int i = 0; i < 32; i += 8) {
    int k = kb + ty + i;
    tile[ty + i][tx] = (k < K) ? in[(long)k * N + nb + tx] : 0.f;
  }
  __syncthreads();
  if (threadIdx.x < 128) {
    int nl = threadIdx.x & 31;
    int nn = nb + nl;
    int kc4 = threadIdx.x >> 5;  // 0..3
    int k0 = kc4 * 8;
    shortx8 o;
#pragma unroll
    for (int j = 0; j < 8; ++j) o[j] = (short)f2bf(tile[k0 + j][nl]);
    int kc = (kb >> 3) + kc4;
    *(shortx8*)(out + (long)(nn >> 7) * Kpad * 128 + (long)kc * 1024 + (nn & 127) * 8) = o;
  }
}

// ---------------- bf16 MFMA GEMM — packed operands, 2-DEEP prefetch, 3 LDS buffers ----------------
// (R10/R12-proven: ~187us/dispatch, MfmaUtil 30, ~93% of the 2-phase structural
// ceiling (m233). R13's 256^2 variant regressed (1 block/CU residency) —
// 128^2 is the optimum for this structure. Byte-identical to R12 here.)
// C[M,N] = A[M,K] * Bt[N,K]^T, both operands packed [*/128][K/8][128][8].
// Per K-step: issue tile k+2's 4 DMA loads -> s_waitcnt vmcnt(8) (tiles
// k+1,k+2 = 8 loads STAY IN FLIGHT across the bare s_barrier; never vmcnt(0)
// mid-loop) -> barrier -> frags + 16 MFMA -> bare barrier.
// Hazard audit (R3/R10): stage target buf (k+2)%3 == (k-1)%3; all reads of that
// buffer retired before iter k-1's trailing barrier (MFMA data-dep drained
// lgkm), and the DMA issues only after this wave passed that barrier -> no WAR
// race. RAW: vmcnt(8) retires tile k's 4 oldest loads; barrier publishes all
// waves' DMA writes before fragment reads.
// Tail ladder: vmcnt(8) -> vmcnt(4) (iter nk-2) -> vmcnt(0) (iter nk-1).
//   0x0F78=vmcnt(8)  0x0F74=vmcnt(4)  0x0F70=vmcnt(0).
// LDS 48KB -> 3 blocks/CU. Requires K%32==0, N%128==0, A packed to grid rows.
template <typename OT>
__global__ __launch_bounds__(256) void mfma_gemm_kernel(const unsigned short* __restrict__ A,
                                                        const unsigned short* __restrict__ Bt,
                                                        OT* __restrict__ C, int M, int N, int K) {
  __shared__ unsigned short As[3][4096];
  __shared__ unsigned short Bs[3][4096];

  int tid = threadIdx.x;
  int lane = tid & 63;
  int w = tid >> 6;
  int wm = w & 1, wn = w >> 1;
  int bn = blockIdx.x * 128;  // N-tile fastest
  int bm = blockIdx.y * 128;
  int quad = lane >> 4, l16 = lane & 15;

  const unsigned short* pA = A + (long)(bm >> 7) * K * 128 + tid * 8;
  const unsigned short* pB = Bt + (long)(bn >> 7) * K * 128 + tid * 8;
  unsigned short* la = &As[0][0] + w * 512;
  unsigned short* lb = &Bs[0][0] + w * 512;

  floatx4 acc[4][4];
#pragma unroll
  for (int i = 0; i < 4; ++i)
#pragma unroll
    for (int j = 0; j < 4; ++j) acc[i][j] = (floatx4){0.f, 0.f, 0.f, 0.f};

  int nk = K >> 5;
  // prologue: tile 0 -> buf0, tile 1 -> buf1
  gload_lds16(pA, la);
  gload_lds16(pA + 2048, la + 2048);
  gload_lds16(pB, lb);
  gload_lds16(pB + 2048, lb + 2048);
  if (nk > 1) {
    gload_lds16(pA + 4096, la + 4096);
    gload_lds16(pA + 4096 + 2048, la + 4096 + 2048);
    gload_lds16(pB + 4096, lb + 4096);
    gload_lds16(pB + 4096 + 2048, lb + 4096 + 2048);
  }

  int cur = 0, st = 2;
  for (int k = 0; k < nk; ++k) {
    if (k + 2 < nk) {
      const unsigned short* qA = pA + (long)(k + 2) * 4096;
      const unsigned short* qB = pB + (long)(k + 2) * 4096;
      unsigned short* da = la + st * 4096;
      unsigned short* db = lb + st * 4096;
      gload_lds16(qA, da);
      gload_lds16(qA + 2048, da + 2048);
      gload_lds16(qB, db);
      gload_lds16(qB + 2048, db + 2048);
      __builtin_amdgcn_s_waitcnt(0x0F78);  // vmcnt(8): tile k done, k+1/k+2 in flight
    } else if (k + 1 < nk) {
      __builtin_amdgcn_s_waitcnt(0x0F74);  // vmcnt(4): tile k done, k+1 in flight
    } else {
      __builtin_amdgcn_s_waitcnt(0x0F70);  // vmcnt(0): drain final tile
    }
    __builtin_amdgcn_s_barrier();  // bare barrier: in-flight DMA untouched

    shortx8 a[4], b[4];
#pragma unroll
    for (int i = 0; i < 4; ++i) {
      a[i] = *(const shortx8*)(&As[cur][(quad * 128 + wm * 64 + i * 16 + l16) * 8]);
      b[i] = *(const shortx8*)(&Bs[cur][(quad * 128 + wn * 64 + i * 16 + l16) * 8]);
    }
#pragma unroll
    for (int i = 0; i < 4; ++i)
#pragma unroll
      for (int j = 0; j < 4; ++j)
        acc[i][j] = __builtin_amdgcn_mfma_f32_16x16x32_bf16(a[i], b[j], acc[i][j], 0, 0, 0);

    // WAR guard: all reads of the buffer the next stage overwrites retired here.
    __builtin_amdgcn_s_barrier();
    cur = (cur == 2) ? 0 : cur + 1;
    st = (st == 2) ? 0 : st + 1;
  }

  // epilogue: C/D layout col=lane&15, row=quad*4+reg
  int orow0 = bm + wm * 64 + quad * 4;
  int ocol0 = bn + wn * 64 + l16;
#pragma unroll
  for (int i = 0; i < 4; ++i)
#pragma unroll
    for (int j = 0; j < 4; ++j)
#pragma unroll
      for (int r2 = 0; r2 < 4; ++r2) {
        int rr = orow0 + i * 16 + r2;
        if (rr < M) store_out(&C[(long)rr * N + ocol0 + j * 16], acc[i][j][r2]);
      }
}

// ---------------- attention coefficients from bf16 h ----------------
__global__ __launch_bounds__(256) void att_coef_kernel(const unsigned short* __restrict__ h,
                                                       const float* __restrict__ att_s,
                                                       const float* __restrict__ att_d,
                                                       float* __restrict__ a_s,
                                                       float* __restrict__ a_d, int n, int H,
                                                       int C) {
  int wave = (int)((blockIdx.x * blockDim.x + threadIdx.x) >> 6);
  int lane = threadIdx.x & 63;
  if (wave >= n) return;
  const unsigned short* row = h + (long)wave * H * C;
  for (int hh = 0; hh < H; ++hh) {
    float s = 0.f, d = 0.f;
    for (int c = lane; c < C; c += 64) {
      float v = bf2f(row[hh * C + c]);
      s += v * att_s[hh * C + c];
      d += v * att_d[hh * C + c];
    }
#pragma unroll
    for (int o = 32; o > 0; o >>= 1) {
      s += __shfl_down(s, o, 64);
      d += __shfl_down(d, o, 64);
    }
    if (lane == 0) {
      a_s[(long)wave * H + hh] = s;
      a_d[(long)wave * H + hh] = d;
    }
  }
}

// ---------------- per-(dst,head) segment softmax over CSR — 2-pass, denom hoisted ----------------
// R13 change: the per-edge normalization is hoisted into the aggregates
// (sum_j (ex_j/denom)*h_j == (1/denom)*sum_j ex_j*h_j), so pass 3 (8.8MB
// read-modify-write of alpha) is GONE; dinv[dst*H+hh] = 1/ssum is written
// instead. Pass 2 reuses the cached e from pass 1 (stored in alpha) instead of
// re-gathering a_src (drops 2.2M scattered 4B reads per call).
__global__ void edge_softmax_kernel(const float* __restrict__ a_src,
                                    const float* __restrict__ a_dst,
                                    const int* __restrict__ offs, const int* __restrict__ srcs,
                                    float* __restrict__ alpha, float* __restrict__ dinv, int n,
                                    int H) {
  int idx = blockIdx.x * blockDim.x + threadIdx.x;
  if (idx >= n * H) return;
  int dstn = idx / H;
  int hh = idx - dstn * H;
  int beg = offs[dstn], end = offs[dstn + 1];
  float ad = a_dst[idx];
  float m = -1e30f;
  for (int j = beg; j < end; ++j) {
    float e = a_src[srcs[j] * H + hh] + ad;
    e = e > 0.f ? e : NEG_SLOPE * e;
    alpha[(long)j * H + hh] = e;
    m = fmaxf(m, e);
  }
  float ssum = 0.f;
  for (int j = beg; j < end; ++j) {
    float ex = __expf(alpha[(long)j * H + hh] - m);
    alpha[(long)j * H + hh] = ex;
    ssum += ex;
  }
  dinv[idx] = 1.f / ssum;
}

// ---------------- layer-1 aggregation: bf16 h -> packed bf16 xb2 (R5/R10-proven) ----------------
// One dst per block: the WHOLE block walks one edge list in lockstep; lanes
// read consecutive fids of the same src row -> fully coalesced reads (the 563MB
// side). Packed write is 16B-strided (write amplification) but writes are only
// ~52MB — R11 proved trading read coalescing for write coalescing loses 64us.
// R13: alpha holds UNNORMALIZED ex; multiply by dinv[dst,hh] once at the end.
__global__ __launch_bounds__(320) void aggregate1_kernel(const unsigned short* __restrict__ h,
                                                         const float* __restrict__ alpha,
                                                         const float* __restrict__ dinv,
                                                         const int* __restrict__ offs,
                                                         const int* __restrict__ srcs,
                                                         const float* __restrict__ bias,
                                                         unsigned short* __restrict__ out, int H,
                                                         int C, int HC) {
  int dstn = blockIdx.x;
  int t = threadIdx.x;
  int beg = offs[dstn], end = offs[dstn + 1];
  int nf8 = HC >> 3;
  for (int fid = t; fid < nf8; fid += blockDim.x) {
    int hh = (fid << 3) / C;
    float acc[8];
#pragma unroll
    for (int i = 0; i < 8; ++i) acc[i] = 0.f;
    for (int j = beg; j < end; ++j) {
      int s = srcs[j];
      float al = alpha[(long)j * H + hh];
      shortx8 r = ((const shortx8*)(h + (long)s * HC))[fid];
#pragma unroll
      for (int i = 0; i < 8; ++i) acc[i] = fmaf(al, bf2f((unsigned short)r[i]), acc[i]);
    }
    float di = dinv[(long)dstn * H + hh];
    shortx8 o;
#pragma unroll
    for (int i = 0; i < 8; ++i) {
      float bb = bias[(fid << 3) + i];
      o[i] = (short)f2bf(fmaxf(fmaf(acc[i], di, bb), 0.f));
    }
    // packed layout: (row=dstn, kc=fid) -> [dstn>>7][fid][dstn&127][8]
    *(shortx8*)(out + (long)(dstn >> 7) * HC * 128 + (long)fid * 1024 + (dstn & 127) * 8) = o;
  }
}

// ---------------- layer-2 aggregation with head-mean: vectorized, NO atomics (R12-proven) ----------------
// R13: multiply per-head accumulator by dinv[dst,hh] before the head fold.
__global__ __launch_bounds__(256) void aggregate2_kernel(const unsigned short* __restrict__ h,
                                                         const float* __restrict__ alpha,
                                                         const float* __restrict__ dinv,
                                                         const int* __restrict__ offs,
                                                         const int* __restrict__ srcs,
                                                         const float* __restrict__ bias,
                                                         float* __restrict__ out, int H, int C) {
  __shared__ float smem[16 * 256];  // nHgrp x C, C<=256
  int dstn = blockIdx.x;
  int t = threadIdx.x;
  int HC = H * C;
  int nc8 = C >> 3;                 // 16 for C=128
  int c8 = t & (nc8 - 1);
  int hgrp = t >> __builtin_ctz(nc8);  // 0..nHgrp-1
  int nHgrp = 256 >> __builtin_ctz(nc8);
  int beg = offs[dstn], end = offs[dstn + 1];

  float acc[2][8];
#pragma unroll
  for (int hi = 0; hi < 2; ++hi)
#pragma unroll
    for (int i = 0; i < 8; ++i) acc[hi][i] = 0.f;

  for (int j = beg; j < end; ++j) {
    int s = srcs[j];
    const unsigned short* row = h + (long)s * HC;
    const float* al = alpha + (long)j * H;
#pragma unroll
    for (int hi = 0; hi < 2; ++hi) {
      int hh = hgrp + hi * nHgrp;
      if (hh < H) {
        float a = al[hh];
        shortx8 r = *(const shortx8*)(row + hh * C + c8 * 8);
#pragma unroll
        for (int i = 0; i < 8; ++i) acc[hi][i] = fmaf(a, bf2f((unsigned short)r[i]), acc[hi][i]);
      }
    }
  }
  // normalize per head, fold the two head-slices, park in smem[hgrp][c]
  float d0 = (hgrp < H) ? dinv[(long)dstn * H + hgrp] : 0.f;
  float d1 = (hgrp + nHgrp < H) ? dinv[(long)dstn * H + hgrp + nHgrp] : 0.f;
#pragma unroll
  for (int i = 0; i < 8; ++i)
    smem[hgrp * C + c8 * 8 + i] = acc[0][i] * d0 + acc[1][i] * d1;
  __syncthreads();
  float invH = 1.f / (float)H;
  for (int c = t; c < C; c += 256) {
    float s = 0.f;
    for (int g = 0; g < nHgrp; ++g) s += smem[g * C + c];
    float v = s * invH + bias[c];
    out[(long)dstn * C + c] = v > 0.f ? v : 0.f;
  }
}

// ---------------- host ----------------
static inline size_t align256(size_t x) { return (x + 255) & ~(size_t)255; }

extern "C" void kernel_launch(void* const* d_in, const int* in_sizes, int n_in, void* d_out,
                              int out_size, void* d_ws, size_t ws_size, hipStream_t stream) {
  const float* x        = (const float*)d_in[0];
  const void*  ei       = d_in[1];
  const float* W1       = (const float*)d_in[2];
  const float* att_src1 = (const float*)d_in[3];
  const float* att_dst1 = (const float*)d_in[4];
  const float* b1       = (const float*)d_in[5];
  const float* W2       = (const float*)d_in[6];
  const float* att_src2 = (const float*)d_in[7];
  const float* att_dst2 = (const float*)d_in[8];
  const float* b2       = (const float*)d_in[9];
  float* out = (float*)d_out;

  const int C2  = in_sizes[9];       // 128
  const int H   = in_sizes[7] / C2;  // 20
  const int HC1 = in_sizes[5];       // 2560
  const int C1  = HC1 / H;           // 128
  const int G   = in_sizes[2] / HC1; // 2000
  const int Nn  = in_sizes[0] / G;   // 10000
  const int E   = in_sizes[1] / 2;   // 100000
  const int HC2 = H * C2;            // 2560
  const int Et  = E + Nn;
  const int Mpad = ((Nn + 127) / 128) * 128;
  const int K1pad = ((G + 31) / 32) * 32;  // 2048

  // workspace layout — R12-exact + dinv
  char* p = (char*)d_ws;
  size_t off = 0;
  unsigned short* hb  = (unsigned short*)(p + off); off = align256(off + (size_t)Mpad * (HC1 > HC2 ? HC1 : HC2) * 2);
  unsigned short* xb  = (unsigned short*)(p + off); off = align256(off + (size_t)Mpad * K1pad * 2);
  unsigned short* xb2 = (unsigned short*)(p + off); off = align256(off + (size_t)Mpad * HC1 * 2);
  unsigned short* W1t = (unsigned short*)(p + off); off = align256(off + (size_t)HC1 * K1pad * 2);
  unsigned short* W2t = (unsigned short*)(p + off); off = align256(off + (size_t)HC2 * HC1 * 2);
  float* a_s   = (float*)(p + off); off = align256(off + (size_t)Nn * H * 4);
  float* a_d   = (float*)(p + off); off = align256(off + (size_t)Nn * H * 4);
  float* dinv  = (float*)(p + off); off = align256(off + (size_t)Nn * H * 4);
  float* alpha = (float*)(p + off); off = align256(off + (size_t)Et * H * 4);
  int* cnt     = (int*)(p + off); off = align256(off + (size_t)Nn * 4);
  int* offs    = (int*)(p + off); off = align256(off + (size_t)(Nn + 1) * 4);
  int* fill    = (int*)(p + off); off = align256(off + (size_t)Nn * 4);
  int* srcs    = (int*)(p + off); off = align256(off + (size_t)Et * 4);
  int* flag64  = (int*)(p + off); off = align256(off + 16);
  (void)ws_size; (void)n_in; (void)out_size;

  const int TB = 256;
  // CSR build
  detect64_kernel<<<1, 1, 0, stream>>>((const unsigned int*)ei, flag64);
  init_cnt_kernel<<<(Nn + TB - 1) / TB, TB, 0, stream>>>(cnt, Nn);
  count_kernel<<<(E + TB - 1) / TB, TB, 0, stream>>>(ei, flag64, E, cnt);
  scan_kernel<<<1, 1024, 0, stream>>>(cnt, offs, Nn);
  init_self_kernel<<<(Nn + TB - 1) / TB, TB, 0, stream>>>(offs, srcs, fill, Nn);
  scatter_kernel<<<(E + TB - 1) / TB, TB, 0, stream>>>(ei, flag64, E, offs, fill, srcs);

  // packed-layout operand prep
  {
    dim3 ga(Mpad / 128, 8);
    pack_a_kernel<<<ga, 256, 0, stream>>>(x, xb, Nn, G, K1pad);
    dim3 g1(K1pad / 32, HC1 / 32);
    transpose_pack_kernel<<<g1, 256, 0, stream>>>(W1, W1t, G, HC1, K1pad);
    dim3 g2(HC1 / 32, HC2 / 32);
    transpose_pack_kernel<<<g2, 256, 0, stream>>>(W2, W2t, HC1, HC2, HC1);
  }

  // layer 1
  {
    dim3 grid(HC1 / 128, Mpad / 128);  // N-tile fastest
    mfma_gemm_kernel<unsigned short><<<grid, 256, 0, stream>>>(xb, W1t, hb, Nn, HC1, K1pad);
  }
  att_coef_kernel<<<(Nn + 3) / 4, 256, 0, stream>>>(hb, att_src1, att_dst1, a_s, a_d, Nn, H, C1);
  edge_softmax_kernel<<<(Nn * H + TB - 1) / TB, TB, 0, stream>>>(a_s, a_d, offs, srcs, alpha, dinv, Nn, H);
  aggregate1_kernel<<<Nn, 320, 0, stream>>>(hb, alpha, dinv, offs, srcs, b1, xb2, H, C1, HC1);

  // layer 2
  {
    dim3 grid(HC2 / 128, Mpad / 128);
    mfma_gemm_kernel<unsigned short><<<grid, 256, 0, stream>>>(xb2, W2t, hb, Nn, HC2, HC1);
  }
  att_coef_kernel<<<(Nn + 3) / 4, 256, 0, stream>>>(hb, att_src2, att_dst2, a_s, a_d, Nn, H, C2);
  edge_softmax_kernel<<<(Nn * H + TB - 1) / TB, TB, 0, stream>>>(a_s, a_d, offs, srcs, alpha, dinv, Nn, H);
  aggregate2_kernel<<<Nn, 256, 0, stream>>>(hb, alpha, dinv, offs, srcs, b2, out, H, C2);
}

// Round 15
// 847.093 us; speedup vs baseline: 1.0382x; 1.0163x over previous
//
#include <hip/hip_runtime.h>

#define NEG_SLOPE 0.2f

typedef __attribute__((ext_vector_type(4))) float floatx4;
typedef __attribute__((ext_vector_type(8))) short shortx8;

__device__ __forceinline__ unsigned short f2bf(float f) {
  union { float f; unsigned int u; } v;
  v.f = f;
  unsigned int r = (v.u + 0x7FFFu + ((v.u >> 16) & 1u)) >> 16;
  return (unsigned short)r;
}
__device__ __forceinline__ float bf2f(unsigned short u) {
  union { unsigned int u; float f; } v;
  v.u = (unsigned int)u << 16;
  return v.f;
}
__device__ __forceinline__ void store_out(float* p, float v) { *p = v; }
__device__ __forceinline__ void store_out(unsigned short* p, float v) { *p = f2bf(v); }

// async global->LDS, 16B per lane, LDS dest = wave-uniform base + lane*16
__device__ __forceinline__ void gload_lds16(const unsigned short* g, unsigned short* l) {
  __builtin_amdgcn_global_load_lds(
      (const __attribute__((address_space(1))) void*)(g),
      (__attribute__((address_space(3))) void*)(l), 16, 0, 0);
}

// ---------------- edge index width detection (int32 vs int64) ----------------
__device__ __forceinline__ int load_edge(const void* ei, long idx, int is64) {
  if (is64) return (int)((const long long*)ei)[idx];
  return ((const int*)ei)[idx];
}

__global__ void detect64_kernel(const unsigned int* __restrict__ p, int* __restrict__ flag) {
  int is64 = 1;
  for (int i = 0; i < 32; ++i)
    if (p[2 * i + 1] != 0u) is64 = 0;
  *flag = is64;
}

// ---------------- CSR build ----------------
__global__ void init_cnt_kernel(int* __restrict__ cnt, int n) {
  int i = blockIdx.x * blockDim.x + threadIdx.x;
  if (i < n) cnt[i] = 1;  // self-loop
}

__global__ void count_kernel(const void* __restrict__ ei, const int* __restrict__ flag, int E,
                             int* __restrict__ cnt) {
  int e = blockIdx.x * blockDim.x + threadIdx.x;
  if (e >= E) return;
  int is64 = *flag;
  int d = load_edge(ei, (long)E + e, is64);
  atomicAdd(&cnt[d], 1);
}

__global__ __launch_bounds__(1024) void scan_kernel(const int* __restrict__ cnt,
                                                    int* __restrict__ offs, int n) {
  __shared__ int partial[1024];
  int t = threadIdx.x;
  int per = (n + 1023) / 1024;
  int beg = t * per;
  int end = min(beg + per, n);
  int sum = 0;
  for (int i = beg; i < end; ++i) sum += cnt[i];
  partial[t] = sum;
  __syncthreads();
  for (int d = 1; d < 1024; d <<= 1) {
    int v = (t >= d) ? partial[t - d] : 0;
    __syncthreads();
    partial[t] += v;
    __syncthreads();
  }
  int excl = (t == 0) ? 0 : partial[t - 1];
  for (int i = beg; i < end; ++i) { offs[i] = excl; excl += cnt[i]; }
  if (t == 1023) offs[n] = partial[1023];
}

__global__ void init_self_kernel(const int* __restrict__ offs, int* __restrict__ srcs,
                                 int* __restrict__ fill, int n) {
  int i = blockIdx.x * blockDim.x + threadIdx.x;
  if (i < n) { srcs[offs[i]] = i; fill[i] = 1; }
}

__global__ void scatter_kernel(const void* __restrict__ ei, const int* __restrict__ flag, int E,
                               const int* __restrict__ offs, int* __restrict__ fill,
                               int* __restrict__ srcs) {
  int e = blockIdx.x * blockDim.x + threadIdx.x;
  if (e >= E) return;
  int is64 = *flag;
  int s = load_edge(ei, e, is64);
  int d = load_edge(ei, (long)E + e, is64);
  int pos = offs[d] + atomicAdd(&fill[d], 1);
  srcs[pos] = s;
}

// ---------------- packers: emit tile-panel-major layout [rt][kc][r128][8] ----------------
// (R5 win: +76% on GEMM. Element (row,k) lives at P[row>>7][k>>3][row&127][k&7],
// so each GEMM K-iter stages one CONTIGUOUS 8KB span per operand.)

// x f32 [M][K] -> packed bf16 [Mpad/128][Kpad/8][128][8]; rows>=M zero-filled.
__global__ __launch_bounds__(256) void pack_a_kernel(const float* __restrict__ in,
                                                     unsigned short* __restrict__ out, int M,
                                                     int K, int Kpad) {
  int rt = blockIdx.x;
  int r = threadIdx.x & 127;
  int kq = threadIdx.x >> 7;  // 0..1
  int row = rt * 128 + r;
  int nkc = Kpad >> 3;
  unsigned short* obase = out + (long)rt * Kpad * 128 + r * 8;
  const float* irow = in + (long)row * K;
  for (int kc = kq + (int)blockIdx.y * 2; kc < nkc; kc += (int)gridDim.y * 2) {
    int k = kc << 3;
    shortx8 o;
    if (row < M && k + 8 <= K && (K & 3) == 0) {
      float4 v0 = *(const float4*)(irow + k);
      float4 v1 = *(const float4*)(irow + k + 4);
      o[0] = (short)f2bf(v0.x); o[1] = (short)f2bf(v0.y);
      o[2] = (short)f2bf(v0.z); o[3] = (short)f2bf(v0.w);
      o[4] = (short)f2bf(v1.x); o[5] = (short)f2bf(v1.y);
      o[6] = (short)f2bf(v1.z); o[7] = (short)f2bf(v1.w);
    } else {
#pragma unroll
      for (int i = 0; i < 8; ++i) {
        int kk = k + i;
        float v = (row < M && kk < K) ? irow[kk] : 0.f;
        o[i] = (short)f2bf(v);
      }
    }
    *(shortx8*)(obase + (long)kc * 1024) = o;
  }
}

// W f32 [K][N] -> packed bf16 [N/128][Kpad/8][128][8] (transpose + pack).
__global__ __launch_bounds__(256) void transpose_pack_kernel(const float* __restrict__ in,
                                                             unsigned short* __restrict__ out,
                                                             int K, int N, int Kpad) {
  __shared__ float tile[32][33];
  int kb = blockIdx.x * 32;
  int nb = blockIdx.y * 32;
  int tx = threadIdx.x & 31;
  int ty = threadIdx.x >> 5;
#pragma unroll
  for (int i = 0; i < 32; i += 8) {
    int k = kb + ty + i;
    tile[ty + i][tx] = (k < K) ? in[(long)k * N + nb + tx] : 0.f;
  }
  __syncthreads();
  if (threadIdx.x < 128) {
    int nl = threadIdx.x & 31;
    int nn = nb + nl;
    int kc4 = threadIdx.x >> 5;  // 0..3
    int k0 = kc4 * 8;
    shortx8 o;
#pragma unroll
    for (int j = 0; j < 8; ++j) o[j] = (short)f2bf(tile[k0 + j][nl]);
    int kc = (kb >> 3) + kc4;
    *(shortx8*)(out + (long)(nn >> 7) * Kpad * 128 + (long)kc * 1024 + (nn & 127) * 8) = o;
  }
}

// ---------------- bf16 MFMA GEMM — packed operands, 2-DEEP prefetch, 3 LDS buffers ----------------
// (R10/R12/R14-proven: ~188us/dispatch, MfmaUtil 30, ~93% of the 2-phase
// structural ceiling (m233). Byte-identical here.)
// C[M,N] = A[M,K] * Bt[N,K]^T, both operands packed [*/128][K/8][128][8].
// Per K-step: issue tile k+2's 4 DMA loads -> s_waitcnt vmcnt(8) (tiles
// k+1,k+2 = 8 loads STAY IN FLIGHT across the bare s_barrier; never vmcnt(0)
// mid-loop) -> barrier -> frags + 16 MFMA -> bare barrier.
// Tail ladder: vmcnt(8) -> vmcnt(4) (iter nk-2) -> vmcnt(0) (iter nk-1).
//   0x0F78=vmcnt(8)  0x0F74=vmcnt(4)  0x0F70=vmcnt(0).
// LDS 48KB -> 3 blocks/CU. Requires K%32==0, N%128==0, A packed to grid rows.
template <typename OT>
__global__ __launch_bounds__(256) void mfma_gemm_kernel(const unsigned short* __restrict__ A,
                                                        const unsigned short* __restrict__ Bt,
                                                        OT* __restrict__ C, int M, int N, int K) {
  __shared__ unsigned short As[3][4096];
  __shared__ unsigned short Bs[3][4096];

  int tid = threadIdx.x;
  int lane = tid & 63;
  int w = tid >> 6;
  int wm = w & 1, wn = w >> 1;
  int bn = blockIdx.x * 128;  // N-tile fastest
  int bm = blockIdx.y * 128;
  int quad = lane >> 4, l16 = lane & 15;

  const unsigned short* pA = A + (long)(bm >> 7) * K * 128 + tid * 8;
  const unsigned short* pB = Bt + (long)(bn >> 7) * K * 128 + tid * 8;
  unsigned short* la = &As[0][0] + w * 512;
  unsigned short* lb = &Bs[0][0] + w * 512;

  floatx4 acc[4][4];
#pragma unroll
  for (int i = 0; i < 4; ++i)
#pragma unroll
    for (int j = 0; j < 4; ++j) acc[i][j] = (floatx4){0.f, 0.f, 0.f, 0.f};

  int nk = K >> 5;
  // prologue: tile 0 -> buf0, tile 1 -> buf1
  gload_lds16(pA, la);
  gload_lds16(pA + 2048, la + 2048);
  gload_lds16(pB, lb);
  gload_lds16(pB + 2048, lb + 2048);
  if (nk > 1) {
    gload_lds16(pA + 4096, la + 4096);
    gload_lds16(pA + 4096 + 2048, la + 4096 + 2048);
    gload_lds16(pB + 4096, lb + 4096);
    gload_lds16(pB + 4096 + 2048, lb + 4096 + 2048);
  }

  int cur = 0, st = 2;
  for (int k = 0; k < nk; ++k) {
    if (k + 2 < nk) {
      const unsigned short* qA = pA + (long)(k + 2) * 4096;
      const unsigned short* qB = pB + (long)(k + 2) * 4096;
      unsigned short* da = la + st * 4096;
      unsigned short* db = lb + st * 4096;
      gload_lds16(qA, da);
      gload_lds16(qA + 2048, da + 2048);
      gload_lds16(qB, db);
      gload_lds16(qB + 2048, db + 2048);
      __builtin_amdgcn_s_waitcnt(0x0F78);  // vmcnt(8): tile k done, k+1/k+2 in flight
    } else if (k + 1 < nk) {
      __builtin_amdgcn_s_waitcnt(0x0F74);  // vmcnt(4): tile k done, k+1 in flight
    } else {
      __builtin_amdgcn_s_waitcnt(0x0F70);  // vmcnt(0): drain final tile
    }
    __builtin_amdgcn_s_barrier();  // bare barrier: in-flight DMA untouched

    shortx8 a[4], b[4];
#pragma unroll
    for (int i = 0; i < 4; ++i) {
      a[i] = *(const shortx8*)(&As[cur][(quad * 128 + wm * 64 + i * 16 + l16) * 8]);
      b[i] = *(const shortx8*)(&Bs[cur][(quad * 128 + wn * 64 + i * 16 + l16) * 8]);
    }
#pragma unroll
    for (int i = 0; i < 4; ++i)
#pragma unroll
      for (int j = 0; j < 4; ++j)
        acc[i][j] = __builtin_amdgcn_mfma_f32_16x16x32_bf16(a[i], b[j], acc[i][j], 0, 0, 0);

    // WAR guard: all reads of the buffer the next stage overwrites retired here.
    __builtin_amdgcn_s_barrier();
    cur = (cur == 2) ? 0 : cur + 1;
    st = (st == 2) ? 0 : st + 1;
  }

  // epilogue: C/D layout col=lane&15, row=quad*4+reg
  int orow0 = bm + wm * 64 + quad * 4;
  int ocol0 = bn + wn * 64 + l16;
#pragma unroll
  for (int i = 0; i < 4; ++i)
#pragma unroll
    for (int j = 0; j < 4; ++j)
#pragma unroll
      for (int r2 = 0; r2 < 4; ++r2) {
        int rr = orow0 + i * 16 + r2;
        if (rr < M) store_out(&C[(long)rr * N + ocol0 + j * 16], acc[i][j][r2]);
      }
}

// ---------------- attention coefficients from bf16 h ----------------
__global__ __launch_bounds__(256) void att_coef_kernel(const unsigned short* __restrict__ h,
                                                       const float* __restrict__ att_s,
                                                       const float* __restrict__ att_d,
                                                       float* __restrict__ a_s,
                                                       float* __restrict__ a_d, int n, int H,
                                                       int C) {
  int wave = (int)((blockIdx.x * blockDim.x + threadIdx.x) >> 6);
  int lane = threadIdx.x & 63;
  if (wave >= n) return;
  const unsigned short* row = h + (long)wave * H * C;
  for (int hh = 0; hh < H; ++hh) {
    float s = 0.f, d = 0.f;
    for (int c = lane; c < C; c += 64) {
      float v = bf2f(row[hh * C + c]);
      s += v * att_s[hh * C + c];
      d += v * att_d[hh * C + c];
    }
#pragma unroll
    for (int o = 32; o > 0; o >>= 1) {
      s += __shfl_down(s, o, 64);
      d += __shfl_down(d, o, 64);
    }
    if (lane == 0) {
      a_s[(long)wave * H + hh] = s;
      a_d[(long)wave * H + hh] = d;
    }
  }
}

// ---------------- per-(dst,head) segment softmax over CSR — 2-pass, denom hoisted (R14) ----------------
__global__ void edge_softmax_kernel(const float* __restrict__ a_src,
                                    const float* __restrict__ a_dst,
                                    const int* __restrict__ offs, const int* __restrict__ srcs,
                                    float* __restrict__ alpha, float* __restrict__ dinv, int n,
                                    int H) {
  int idx = blockIdx.x * blockDim.x + threadIdx.x;
  if (idx >= n * H) return;
  int dstn = idx / H;
  int hh = idx - dstn * H;
  int beg = offs[dstn], end = offs[dstn + 1];
  float ad = a_dst[idx];
  float m = -1e30f;
  for (int j = beg; j < end; ++j) {
    float e = a_src[srcs[j] * H + hh] + ad;
    e = e > 0.f ? e : NEG_SLOPE * e;
    alpha[(long)j * H + hh] = e;
    m = fmaxf(m, e);
  }
  float ssum = 0.f;
  for (int j = beg; j < end; ++j) {
    float ex = __expf(alpha[(long)j * H + hh] - m);
    alpha[(long)j * H + hh] = ex;
    ssum += ex;
  }
  dinv[idx] = 1.f / ssum;
}

// ---------------- layer-1 aggregation: lockstep reads + LDS-buffered coalesced packed writes ----------------
// R15: combines R5's proven READ pattern (per dst, the whole block walks ONE
// edge list in lockstep; lanes read consecutive fids of the same src row) with
// coalesced packed WRITES (the R5 form's weakness: 320 isolated 16B stores at
// 2KB stride per dst = every 64B line filled for a 16B write, ~4x write-path
// amplification on 52MB). One block = 8 CONSECUTIVE dsts processed SERIALLY;
// each dst's 5KB output row is parked in LDS; after 8 dsts one write phase
// emits, per fid, lanes sub=0..7 -> 8 consecutive dst cells = contiguous 128B
// (packed layout: for fixed kc, consecutive rows are consecutive 16B cells;
// 8|128 so a block never crosses a row-tile).
// LDS: [8][320*8 + 8 pad] shorts ~= 40KB; pad makes write-phase ds_read stride
// 5136B -> lanes hit banks 4*sub -> conflict-free b128 reads. 4 blocks/CU.
// dst in [Nn, Mpad): beg=end -> writes relu(bias) garbage rows; GEMM epilogue
// guards rr<M so they never reach the output.
__global__ __launch_bounds__(320) void aggregate1_kernel(const unsigned short* __restrict__ h,
                                                         const float* __restrict__ alpha,
                                                         const float* __restrict__ dinv,
                                                         const int* __restrict__ offs,
                                                         const int* __restrict__ srcs,
                                                         const float* __restrict__ bias,
                                                         unsigned short* __restrict__ out, int H,
                                                         int C, int HC, int Nn) {
  __shared__ unsigned short lds[8 * 2568];  // 8 dsts x (320 fids x 8 + 8 pad) shorts
  int t = threadIdx.x;
  int d0 = blockIdx.x * 8;
  int nf8 = HC >> 3;  // 320
  int fid = t;        // one fid per thread (blockDim == nf8)
  int hh = (fid << 3) / C;
  float bb[8];
#pragma unroll
  for (int i = 0; i < 8; ++i) bb[i] = bias[(fid << 3) + i];

  for (int ds = 0; ds < 8; ++ds) {
    int dst = d0 + ds;
    int beg = 0, end = 0;
    float di = 0.f;
    if (dst < Nn) {
      beg = offs[dst];
      end = offs[dst + 1];
      di = dinv[(long)dst * H + hh];
    }
    float acc[8];
#pragma unroll
    for (int i = 0; i < 8; ++i) acc[i] = 0.f;
    for (int j = beg; j < end; ++j) {
      int s = srcs[j];
      float al = alpha[(long)j * H + hh];
      shortx8 r = ((const shortx8*)(h + (long)s * HC))[fid];
#pragma unroll
      for (int i = 0; i < 8; ++i) acc[i] = fmaf(al, bf2f((unsigned short)r[i]), acc[i]);
    }
    shortx8 o;
#pragma unroll
    for (int i = 0; i < 8; ++i) o[i] = (short)f2bf(fmaxf(fmaf(acc[i], di, bb[i]), 0.f));
    *(shortx8*)&lds[ds * 2568 + fid * 8] = o;
  }
  __syncthreads();
  // write phase: sub = t&7 (dst), fg = t>>3 (0..39); fid = fg + 40*it
  int sub = t & 7;
  int fg = t >> 3;
  int dst = d0 + sub;
  unsigned short* obase = out + (long)(dst >> 7) * HC * 128 + (dst & 127) * 8;
#pragma unroll
  for (int it = 0; it < 8; ++it) {
    int f = fg + 40 * it;
    shortx8 v = *(const shortx8*)&lds[sub * 2568 + f * 8];
    *(shortx8*)(obase + (long)f * 1024) = v;
  }
}

// ---------------- layer-2 aggregation with head-mean: vectorized, NO atomics (R12/R14-proven) ----------------
__global__ __launch_bounds__(256) void aggregate2_kernel(const unsigned short* __restrict__ h,
                                                         const float* __restrict__ alpha,
                                                         const float* __restrict__ dinv,
                                                         const int* __restrict__ offs,
                                                         const int* __restrict__ srcs,
                                                         const float* __restrict__ bias,
                                                         float* __restrict__ out, int H, int C) {
  __shared__ float smem[16 * 256];  // nHgrp x C, C<=256
  int dstn = blockIdx.x;
  int t = threadIdx.x;
  int HC = H * C;
  int nc8 = C >> 3;                 // 16 for C=128
  int c8 = t & (nc8 - 1);
  int hgrp = t >> __builtin_ctz(nc8);  // 0..nHgrp-1
  int nHgrp = 256 >> __builtin_ctz(nc8);
  int beg = offs[dstn], end = offs[dstn + 1];

  float acc[2][8];
#pragma unroll
  for (int hi = 0; hi < 2; ++hi)
#pragma unroll
    for (int i = 0; i < 8; ++i) acc[hi][i] = 0.f;

  for (int j = beg; j < end; ++j) {
    int s = srcs[j];
    const unsigned short* row = h + (long)s * HC;
    const float* al = alpha + (long)j * H;
#pragma unroll
    for (int hi = 0; hi < 2; ++hi) {
      int hh = hgrp + hi * nHgrp;
      if (hh < H) {
        float a = al[hh];
        shortx8 r = *(const shortx8*)(row + hh * C + c8 * 8);
#pragma unroll
        for (int i = 0; i < 8; ++i) acc[hi][i] = fmaf(a, bf2f((unsigned short)r[i]), acc[hi][i]);
      }
    }
  }
  // normalize per head, fold the two head-slices, park in smem[hgrp][c]
  float d0 = (hgrp < H) ? dinv[(long)dstn * H + hgrp] : 0.f;
  float d1 = (hgrp + nHgrp < H) ? dinv[(long)dstn * H + hgrp + nHgrp] : 0.f;
#pragma unroll
  for (int i = 0; i < 8; ++i)
    smem[hgrp * C + c8 * 8 + i] = acc[0][i] * d0 + acc[1][i] * d1;
  __syncthreads();
  float invH = 1.f / (float)H;
  for (int c = t; c < C; c += 256) {
    float s = 0.f;
    for (int g = 0; g < nHgrp; ++g) s += smem[g * C + c];
    float v = s * invH + bias[c];
    out[(long)dstn * C + c] = v > 0.f ? v : 0.f;
  }
}

// ---------------- host ----------------
static inline size_t align256(size_t x) { return (x + 255) & ~(size_t)255; }

extern "C" void kernel_launch(void* const* d_in, const int* in_sizes, int n_in, void* d_out,
                              int out_size, void* d_ws, size_t ws_size, hipStream_t stream) {
  const float* x        = (const float*)d_in[0];
  const void*  ei       = d_in[1];
  const float* W1       = (const float*)d_in[2];
  const float* att_src1 = (const float*)d_in[3];
  const float* att_dst1 = (const float*)d_in[4];
  const float* b1       = (const float*)d_in[5];
  const float* W2       = (const float*)d_in[6];
  const float* att_src2 = (const float*)d_in[7];
  const float* att_dst2 = (const float*)d_in[8];
  const float* b2       = (const float*)d_in[9];
  float* out = (float*)d_out;

  const int C2  = in_sizes[9];       // 128
  const int H   = in_sizes[7] / C2;  // 20
  const int HC1 = in_sizes[5];       // 2560
  const int C1  = HC1 / H;           // 128
  const int G   = in_sizes[2] / HC1; // 2000
  const int Nn  = in_sizes[0] / G;   // 10000
  const int E   = in_sizes[1] / 2;   // 100000
  const int HC2 = H * C2;            // 2560
  const int Et  = E + Nn;
  const int Mpad = ((Nn + 127) / 128) * 128;
  const int K1pad = ((G + 31) / 32) * 32;  // 2048

  // workspace layout — R14-exact
  char* p = (char*)d_ws;
  size_t off = 0;
  unsigned short* hb  = (unsigned short*)(p + off); off = align256(off + (size_t)Mpad * (HC1 > HC2 ? HC1 : HC2) * 2);
  unsigned short* xb  = (unsigned short*)(p + off); off = align256(off + (size_t)Mpad * K1pad * 2);
  unsigned short* xb2 = (unsigned short*)(p + off); off = align256(off + (size_t)Mpad * HC1 * 2);
  unsigned short* W1t = (unsigned short*)(p + off); off = align256(off + (size_t)HC1 * K1pad * 2);
  unsigned short* W2t = (unsigned short*)(p + off); off = align256(off + (size_t)HC2 * HC1 * 2);
  float* a_s   = (float*)(p + off); off = align256(off + (size_t)Nn * H * 4);
  float* a_d   = (float*)(p + off); off = align256(off + (size_t)Nn * H * 4);
  float* dinv  = (float*)(p + off); off = align256(off + (size_t)Nn * H * 4);
  float* alpha = (float*)(p + off); off = align256(off + (size_t)Et * H * 4);
  int* cnt     = (int*)(p + off); off = align256(off + (size_t)Nn * 4);
  int* offs    = (int*)(p + off); off = align256(off + (size_t)(Nn + 1) * 4);
  int* fill    = (int*)(p + off); off = align256(off + (size_t)Nn * 4);
  int* srcs    = (int*)(p + off); off = align256(off + (size_t)Et * 4);
  int* flag64  = (int*)(p + off); off = align256(off + 16);
  (void)ws_size; (void)n_in; (void)out_size;

  const int TB = 256;
  // CSR build
  detect64_kernel<<<1, 1, 0, stream>>>((const unsigned int*)ei, flag64);
  init_cnt_kernel<<<(Nn + TB - 1) / TB, TB, 0, stream>>>(cnt, Nn);
  count_kernel<<<(E + TB - 1) / TB, TB, 0, stream>>>(ei, flag64, E, cnt);
  scan_kernel<<<1, 1024, 0, stream>>>(cnt, offs, Nn);
  init_self_kernel<<<(Nn + TB - 1) / TB, TB, 0, stream>>>(offs, srcs, fill, Nn);
  scatter_kernel<<<(E + TB - 1) / TB, TB, 0, stream>>>(ei, flag64, E, offs, fill, srcs);

  // packed-layout operand prep
  {
    dim3 ga(Mpad / 128, 8);
    pack_a_kernel<<<ga, 256, 0, stream>>>(x, xb, Nn, G, K1pad);
    dim3 g1(K1pad / 32, HC1 / 32);
    transpose_pack_kernel<<<g1, 256, 0, stream>>>(W1, W1t, G, HC1, K1pad);
    dim3 g2(HC1 / 32, HC2 / 32);
    transpose_pack_kernel<<<g2, 256, 0, stream>>>(W2, W2t, HC1, HC2, HC1);
  }

  // layer 1
  {
    dim3 grid(HC1 / 128, Mpad / 128);  // N-tile fastest
    mfma_gemm_kernel<unsigned short><<<grid, 256, 0, stream>>>(xb, W1t, hb, Nn, HC1, K1pad);
  }
  att_coef_kernel<<<(Nn + 3) / 4, 256, 0, stream>>>(hb, att_src1, att_dst1, a_s, a_d, Nn, H, C1);
  edge_softmax_kernel<<<(Nn * H + TB - 1) / TB, TB, 0, stream>>>(a_s, a_d, offs, srcs, alpha, dinv, Nn, H);
  aggregate1_kernel<<<Mpad / 8, 320, 0, stream>>>(hb, alpha, dinv, offs, srcs, b1, xb2, H, C1, HC1, Nn);

  // layer 2
  {
    dim3 grid(HC2 / 128, Mpad / 128);
    mfma_gemm_kernel<unsigned short><<<grid, 256, 0, stream>>>(xb2, W2t, hb, Nn, HC2, HC1);
  }
  att_coef_kernel<<<(Nn + 3) / 4, 256, 0, stream>>>(hb, att_src2, att_dst2, a_s, a_d, Nn, H, C2);
  edge_softmax_kernel<<<(Nn * H + TB - 1) / TB, TB, 0, stream>>>(a_s, a_d, offs, srcs, alpha, dinv, Nn, H);
  aggregate2_kernel<<<Nn, 256, 0, stream>>>(hb, alpha, dinv, offs, srcs, b2, out, H, C2);
}

// Round 16
// 783.931 us; speedup vs baseline: 1.1219x; 1.0806x over previous
//
#include <hip/hip_runtime.h>

#define NEG_SLOPE 0.2f

typedef __attribute__((ext_vector_type(4))) float floatx4;
typedef __attribute__((ext_vector_type(8))) short shortx8;

__device__ __forceinline__ unsigned short f2bf(float f) {
  union { float f; unsigned int u; } v;
  v.f = f;
  unsigned int r = (v.u + 0x7FFFu + ((v.u >> 16) & 1u)) >> 16;
  return (unsigned short)r;
}
__device__ __forceinline__ float bf2f(unsigned short u) {
  union { unsigned int u; float f; } v;
  v.u = (unsigned int)u << 16;
  return v.f;
}
__device__ __forceinline__ void store_out(float* p, float v) { *p = v; }
__device__ __forceinline__ void store_out(unsigned short* p, float v) { *p = f2bf(v); }

// async global->LDS, 16B per lane, LDS dest = wave-uniform base + lane*16
__device__ __forceinline__ void gload_lds16(const unsigned short* g, unsigned short* l) {
  __builtin_amdgcn_global_load_lds(
      (const __attribute__((address_space(1))) void*)(g),
      (__attribute__((address_space(3))) void*)(l), 16, 0, 0);
}

// ---------------- edge index width detection (int32 vs int64) ----------------
__device__ __forceinline__ int load_edge(const void* ei, long idx, int is64) {
  if (is64) return (int)((const long long*)ei)[idx];
  return ((const int*)ei)[idx];
}

__global__ void detect64_kernel(const unsigned int* __restrict__ p, int* __restrict__ flag) {
  int is64 = 1;
  for (int i = 0; i < 32; ++i)
    if (p[2 * i + 1] != 0u) is64 = 0;
  *flag = is64;
}

// ---------------- CSR build ----------------
__global__ void init_cnt_kernel(int* __restrict__ cnt, int n) {
  int i = blockIdx.x * blockDim.x + threadIdx.x;
  if (i < n) cnt[i] = 1;  // self-loop
}

__global__ void count_kernel(const void* __restrict__ ei, const int* __restrict__ flag, int E,
                             int* __restrict__ cnt) {
  int e = blockIdx.x * blockDim.x + threadIdx.x;
  if (e >= E) return;
  int is64 = *flag;
  int d = load_edge(ei, (long)E + e, is64);
  atomicAdd(&cnt[d], 1);
}

__global__ __launch_bounds__(1024) void scan_kernel(const int* __restrict__ cnt,
                                                    int* __restrict__ offs, int n) {
  __shared__ int partial[1024];
  int t = threadIdx.x;
  int per = (n + 1023) / 1024;
  int beg = t * per;
  int end = min(beg + per, n);
  int sum = 0;
  for (int i = beg; i < end; ++i) sum += cnt[i];
  partial[t] = sum;
  __syncthreads();
  for (int d = 1; d < 1024; d <<= 1) {
    int v = (t >= d) ? partial[t - d] : 0;
    __syncthreads();
    partial[t] += v;
    __syncthreads();
  }
  int excl = (t == 0) ? 0 : partial[t - 1];
  for (int i = beg; i < end; ++i) { offs[i] = excl; excl += cnt[i]; }
  if (t == 1023) offs[n] = partial[1023];
}

__global__ void init_self_kernel(const int* __restrict__ offs, int* __restrict__ srcs,
                                 int* __restrict__ fill, int n) {
  int i = blockIdx.x * blockDim.x + threadIdx.x;
  if (i < n) { srcs[offs[i]] = i; fill[i] = 1; }
}

__global__ void scatter_kernel(const void* __restrict__ ei, const int* __restrict__ flag, int E,
                               const int* __restrict__ offs, int* __restrict__ fill,
                               int* __restrict__ srcs) {
  int e = blockIdx.x * blockDim.x + threadIdx.x;
  if (e >= E) return;
  int is64 = *flag;
  int s = load_edge(ei, e, is64);
  int d = load_edge(ei, (long)E + e, is64);
  int pos = offs[d] + atomicAdd(&fill[d], 1);
  srcs[pos] = s;
}

// ---------------- packers: emit tile-panel-major layout [rt][kc][r128][8] ----------------
// (R5 win: +76% on GEMM. Element (row,k) lives at P[row>>7][k>>3][row&127][k&7],
// so each GEMM K-iter stages one CONTIGUOUS 8KB span per operand.)

// x f32 [M][K] -> packed bf16 [Mpad/128][Kpad/8][128][8]; rows>=M zero-filled.
__global__ __launch_bounds__(256) void pack_a_kernel(const float* __restrict__ in,
                                                     unsigned short* __restrict__ out, int M,
                                                     int K, int Kpad) {
  int rt = blockIdx.x;
  int r = threadIdx.x & 127;
  int kq = threadIdx.x >> 7;  // 0..1
  int row = rt * 128 + r;
  int nkc = Kpad >> 3;
  unsigned short* obase = out + (long)rt * Kpad * 128 + r * 8;
  const float* irow = in + (long)row * K;
  for (int kc = kq + (int)blockIdx.y * 2; kc < nkc; kc += (int)gridDim.y * 2) {
    int k = kc << 3;
    shortx8 o;
    if (row < M && k + 8 <= K && (K & 3) == 0) {
      float4 v0 = *(const float4*)(irow + k);
      float4 v1 = *(const float4*)(irow + k + 4);
      o[0] = (short)f2bf(v0.x); o[1] = (short)f2bf(v0.y);
      o[2] = (short)f2bf(v0.z); o[3] = (short)f2bf(v0.w);
      o[4] = (short)f2bf(v1.x); o[5] = (short)f2bf(v1.y);
      o[6] = (short)f2bf(v1.z); o[7] = (short)f2bf(v1.w);
    } else {
#pragma unroll
      for (int i = 0; i < 8; ++i) {
        int kk = k + i;
        float v = (row < M && kk < K) ? irow[kk] : 0.f;
        o[i] = (short)f2bf(v);
      }
    }
    *(shortx8*)(obase + (long)kc * 1024) = o;
  }
}

// W f32 [K][N] -> packed bf16 [N/128][Kpad/8][128][8] (transpose + pack).
__global__ __launch_bounds__(256) void transpose_pack_kernel(const float* __restrict__ in,
                                                             unsigned short* __restrict__ out,
                                                             int K, int N, int Kpad) {
  __shared__ float tile[32][33];
  int kb = blockIdx.x * 32;
  int nb = blockIdx.y * 32;
  int tx = threadIdx.x & 31;
  int ty = threadIdx.x >> 5;
#pragma unroll
  for (int i = 0; i < 32; i += 8) {
    int k = kb + ty + i;
    tile[ty + i][tx] = (k < K) ? in[(long)k * N + nb + tx] : 0.f;
  }
  __syncthreads();
  if (threadIdx.x < 128) {
    int nl = threadIdx.x & 31;
    int nn = nb + nl;
    int kc4 = threadIdx.x >> 5;  // 0..3
    int k0 = kc4 * 8;
    shortx8 o;
#pragma unroll
    for (int j = 0; j < 8; ++j) o[j] = (short)f2bf(tile[k0 + j][nl]);
    int kc = (kb >> 3) + kc4;
    *(shortx8*)(out + (long)(nn >> 7) * Kpad * 128 + (long)kc * 1024 + (nn & 127) * 8) = o;
  }
}

// ---------------- bf16 MFMA GEMM — packed operands, 2-DEEP prefetch + FUSED att-coef epilogue ----------------
// (K-loop/sync byte-identical to R10..R15: ~174us, MfmaUtil 33, ~100% of the
// 2-phase structural ceiling (m233 ~607 TF; we measure 609).)
// C[M,N] = A[M,K] * Bt[N,K]^T, both operands packed [*/128][K/8][128][8].
// Per K-step: issue tile k+2's 4 DMA loads -> s_waitcnt vmcnt(8) (tiles
// k+1,k+2 stay in flight across the bare s_barrier; never vmcnt(0) mid-loop)
// -> barrier -> frags + 16 MFMA -> bare barrier.
// Tail ladder: 0x0F78=vmcnt(8) -> 0x0F74=vmcnt(4) -> 0x0F70=vmcnt(0).
//
// R16 fusion: C1=C2=128 == the N-tile width, so each block's column range is
// EXACTLY one head (hh = bn>>7). The att-coef dot products
//   a_s[row][hh] = sum_c h[row][hh*128+c]*att_s[hh][c]   (and a_d)
// are therefore block-local: computed in the epilogue from the fp32 acc
// (pre-bf16-rounding -> closer to the JAX reference than the old separate
// kernel that re-read 52MB of bf16 h). Per thread: 4 att weights, 16
// row-partials, 16-lane __shfl_xor reduce, 2-wave LDS fold (+4KB LDS, 52KB
// total -> still 3 blocks/CU), one guarded store per row. att_coef kernels
// deleted. Requires K%32==0, N%128==0, N==H*128, A packed to grid rows.
template <typename OT>
__global__ __launch_bounds__(256) void mfma_gemm_kernel(const unsigned short* __restrict__ A,
                                                        const unsigned short* __restrict__ Bt,
                                                        OT* __restrict__ C,
                                                        const float* __restrict__ att_s,
                                                        const float* __restrict__ att_d,
                                                        float* __restrict__ a_s,
                                                        float* __restrict__ a_d, int M, int N,
                                                        int K, int H) {
  __shared__ unsigned short As[3][4096];
  __shared__ unsigned short Bs[3][4096];
  __shared__ float red_s[2][128];
  __shared__ float red_d[2][128];

  int tid = threadIdx.x;
  int lane = tid & 63;
  int w = tid >> 6;
  int wm = w & 1, wn = w >> 1;
  int bn = blockIdx.x * 128;  // N-tile fastest
  int bm = blockIdx.y * 128;
  int quad = lane >> 4, l16 = lane & 15;

  const unsigned short* pA = A + (long)(bm >> 7) * K * 128 + tid * 8;
  const unsigned short* pB = Bt + (long)(bn >> 7) * K * 128 + tid * 8;
  unsigned short* la = &As[0][0] + w * 512;
  unsigned short* lb = &Bs[0][0] + w * 512;

  floatx4 acc[4][4];
#pragma unroll
  for (int i = 0; i < 4; ++i)
#pragma unroll
    for (int j = 0; j < 4; ++j) acc[i][j] = (floatx4){0.f, 0.f, 0.f, 0.f};

  int nk = K >> 5;
  // prologue: tile 0 -> buf0, tile 1 -> buf1
  gload_lds16(pA, la);
  gload_lds16(pA + 2048, la + 2048);
  gload_lds16(pB, lb);
  gload_lds16(pB + 2048, lb + 2048);
  if (nk > 1) {
    gload_lds16(pA + 4096, la + 4096);
    gload_lds16(pA + 4096 + 2048, la + 4096 + 2048);
    gload_lds16(pB + 4096, lb + 4096);
    gload_lds16(pB + 4096 + 2048, lb + 4096 + 2048);
  }

  int cur = 0, st = 2;
  for (int k = 0; k < nk; ++k) {
    if (k + 2 < nk) {
      const unsigned short* qA = pA + (long)(k + 2) * 4096;
      const unsigned short* qB = pB + (long)(k + 2) * 4096;
      unsigned short* da = la + st * 4096;
      unsigned short* db = lb + st * 4096;
      gload_lds16(qA, da);
      gload_lds16(qA + 2048, da + 2048);
      gload_lds16(qB, db);
      gload_lds16(qB + 2048, db + 2048);
      __builtin_amdgcn_s_waitcnt(0x0F78);  // vmcnt(8): tile k done, k+1/k+2 in flight
    } else if (k + 1 < nk) {
      __builtin_amdgcn_s_waitcnt(0x0F74);  // vmcnt(4): tile k done, k+1 in flight
    } else {
      __builtin_amdgcn_s_waitcnt(0x0F70);  // vmcnt(0): drain final tile
    }
    __builtin_amdgcn_s_barrier();  // bare barrier: in-flight DMA untouched

    shortx8 a[4], b[4];
#pragma unroll
    for (int i = 0; i < 4; ++i) {
      a[i] = *(const shortx8*)(&As[cur][(quad * 128 + wm * 64 + i * 16 + l16) * 8]);
      b[i] = *(const shortx8*)(&Bs[cur][(quad * 128 + wn * 64 + i * 16 + l16) * 8]);
    }
#pragma unroll
    for (int i = 0; i < 4; ++i)
#pragma unroll
      for (int j = 0; j < 4; ++j)
        acc[i][j] = __builtin_amdgcn_mfma_f32_16x16x32_bf16(a[i], b[j], acc[i][j], 0, 0, 0);

    // WAR guard: all reads of the buffer the next stage overwrites retired here.
    __builtin_amdgcn_s_barrier();
    cur = (cur == 2) ? 0 : cur + 1;
    st = (st == 2) ? 0 : st + 1;
  }

  // ---- fused att-coef partials (this block's 128 cols == head hh) ----
  int hh = bn >> 7;
  float att_sv[4], att_dv[4];
#pragma unroll
  for (int j = 0; j < 4; ++j) {
    int cc = wn * 64 + j * 16 + l16;
    att_sv[j] = att_s[hh * 128 + cc];
    att_dv[j] = att_d[hh * 128 + cc];
  }
#pragma unroll
  for (int i = 0; i < 4; ++i)
#pragma unroll
    for (int r2 = 0; r2 < 4; ++r2) {
      float ps = 0.f, pd = 0.f;
#pragma unroll
      for (int j = 0; j < 4; ++j) {
        float v = acc[i][j][r2];
        ps = fmaf(v, att_sv[j], ps);
        pd = fmaf(v, att_dv[j], pd);
      }
#pragma unroll
      for (int msk = 1; msk < 16; msk <<= 1) {
        ps += __shfl_xor(ps, msk, 64);
        pd += __shfl_xor(pd, msk, 64);
      }
      if (l16 == 0) {
        int row = wm * 64 + quad * 4 + i * 16 + r2;
        red_s[wn][row] = ps;
        red_d[wn][row] = pd;
      }
    }

  // epilogue: C/D layout col=lane&15, row=quad*4+reg
  int orow0 = bm + wm * 64 + quad * 4;
  int ocol0 = bn + wn * 64 + l16;
#pragma unroll
  for (int i = 0; i < 4; ++i)
#pragma unroll
    for (int j = 0; j < 4; ++j)
#pragma unroll
      for (int r2 = 0; r2 < 4; ++r2) {
        int rr = orow0 + i * 16 + r2;
        if (rr < M) store_out(&C[(long)rr * N + ocol0 + j * 16], acc[i][j][r2]);
      }

  __syncthreads();
  if (tid < 128) {
    int rr = bm + tid;
    if (rr < M) {
      a_s[(long)rr * H + hh] = red_s[0][tid] + red_s[1][tid];
      a_d[(long)rr * H + hh] = red_d[0][tid] + red_d[1][tid];
    }
  }
}

// ---------------- per-(dst,head) segment softmax over CSR — 2-pass, denom hoisted (R14) ----------------
__global__ void edge_softmax_kernel(const float* __restrict__ a_src,
                                    const float* __restrict__ a_dst,
                                    const int* __restrict__ offs, const int* __restrict__ srcs,
                                    float* __restrict__ alpha, float* __restrict__ dinv, int n,
                                    int H) {
  int idx = blockIdx.x * blockDim.x + threadIdx.x;
  if (idx >= n * H) return;
  int dstn = idx / H;
  int hh = idx - dstn * H;
  int beg = offs[dstn], end = offs[dstn + 1];
  float ad = a_dst[idx];
  float m = -1e30f;
  for (int j = beg; j < end; ++j) {
    float e = a_src[srcs[j] * H + hh] + ad;
    e = e > 0.f ? e : NEG_SLOPE * e;
    alpha[(long)j * H + hh] = e;
    m = fmaxf(m, e);
  }
  float ssum = 0.f;
  for (int j = beg; j < end; ++j) {
    float ex = __expf(alpha[(long)j * H + hh] - m);
    alpha[(long)j * H + hh] = ex;
    ssum += ex;
  }
  dinv[idx] = 1.f / ssum;
}

// ---------------- layer-1 aggregation: lockstep reads + LDS-buffered coalesced packed writes (R15) ----------------
__global__ __launch_bounds__(320) void aggregate1_kernel(const unsigned short* __restrict__ h,
                                                         const float* __restrict__ alpha,
                                                         const float* __restrict__ dinv,
                                                         const int* __restrict__ offs,
                                                         const int* __restrict__ srcs,
                                                         const float* __restrict__ bias,
                                                         unsigned short* __restrict__ out, int H,
                                                         int C, int HC, int Nn) {
  __shared__ unsigned short lds[8 * 2568];  // 8 dsts x (320 fids x 8 + 8 pad) shorts
  int t = threadIdx.x;
  int d0 = blockIdx.x * 8;
  int nf8 = HC >> 3;  // 320
  int fid = t;        // one fid per thread (blockDim == nf8)
  int hh = (fid << 3) / C;
  float bb[8];
#pragma unroll
  for (int i = 0; i < 8; ++i) bb[i] = bias[(fid << 3) + i];

  for (int ds = 0; ds < 8; ++ds) {
    int dst = d0 + ds;
    int beg = 0, end = 0;
    float di = 0.f;
    if (dst < Nn) {
      beg = offs[dst];
      end = offs[dst + 1];
      di = dinv[(long)dst * H + hh];
    }
    float acc[8];
#pragma unroll
    for (int i = 0; i < 8; ++i) acc[i] = 0.f;
    for (int j = beg; j < end; ++j) {
      int s = srcs[j];
      float al = alpha[(long)j * H + hh];
      shortx8 r = ((const shortx8*)(h + (long)s * HC))[fid];
#pragma unroll
      for (int i = 0; i < 8; ++i) acc[i] = fmaf(al, bf2f((unsigned short)r[i]), acc[i]);
    }
    shortx8 o;
#pragma unroll
    for (int i = 0; i < 8; ++i) o[i] = (short)f2bf(fmaxf(fmaf(acc[i], di, bb[i]), 0.f));
    *(shortx8*)&lds[ds * 2568 + fid * 8] = o;
  }
  __syncthreads();
  // write phase: sub = t&7 (dst), fg = t>>3 (0..39); fid = fg + 40*it
  int sub = t & 7;
  int fg = t >> 3;
  int dst = d0 + sub;
  unsigned short* obase = out + (long)(dst >> 7) * HC * 128 + (dst & 127) * 8;
#pragma unroll
  for (int it = 0; it < 8; ++it) {
    int f = fg + 40 * it;
    shortx8 v = *(const shortx8*)&lds[sub * 2568 + f * 8];
    *(shortx8*)(obase + (long)f * 1024) = v;
  }
}

// ---------------- layer-2 aggregation with head-mean: vectorized, NO atomics (R12/R14-proven) ----------------
__global__ __launch_bounds__(256) void aggregate2_kernel(const unsigned short* __restrict__ h,
                                                         const float* __restrict__ alpha,
                                                         const float* __restrict__ dinv,
                                                         const int* __restrict__ offs,
                                                         const int* __restrict__ srcs,
                                                         const float* __restrict__ bias,
                                                         float* __restrict__ out, int H, int C) {
  __shared__ float smem[16 * 256];  // nHgrp x C, C<=256
  int dstn = blockIdx.x;
  int t = threadIdx.x;
  int HC = H * C;
  int nc8 = C >> 3;                 // 16 for C=128
  int c8 = t & (nc8 - 1);
  int hgrp = t >> __builtin_ctz(nc8);  // 0..nHgrp-1
  int nHgrp = 256 >> __builtin_ctz(nc8);
  int beg = offs[dstn], end = offs[dstn + 1];

  float acc[2][8];
#pragma unroll
  for (int hi = 0; hi < 2; ++hi)
#pragma unroll
    for (int i = 0; i < 8; ++i) acc[hi][i] = 0.f;

  for (int j = beg; j < end; ++j) {
    int s = srcs[j];
    const unsigned short* row = h + (long)s * HC;
    const float* al = alpha + (long)j * H;
#pragma unroll
    for (int hi = 0; hi < 2; ++hi) {
      int hh = hgrp + hi * nHgrp;
      if (hh < H) {
        float a = al[hh];
        shortx8 r = *(const shortx8*)(row + hh * C + c8 * 8);
#pragma unroll
        for (int i = 0; i < 8; ++i) acc[hi][i] = fmaf(a, bf2f((unsigned short)r[i]), acc[hi][i]);
      }
    }
  }
  // normalize per head, fold the two head-slices, park in smem[hgrp][c]
  float d0 = (hgrp < H) ? dinv[(long)dstn * H + hgrp] : 0.f;
  float d1 = (hgrp + nHgrp < H) ? dinv[(long)dstn * H + hgrp + nHgrp] : 0.f;
#pragma unroll
  for (int i = 0; i < 8; ++i)
    smem[hgrp * C + c8 * 8 + i] = acc[0][i] * d0 + acc[1][i] * d1;
  __syncthreads();
  float invH = 1.f / (float)H;
  for (int c = t; c < C; c += 256) {
    float s = 0.f;
    for (int g = 0; g < nHgrp; ++g) s += smem[g * C + c];
    float v = s * invH + bias[c];
    out[(long)dstn * C + c] = v > 0.f ? v : 0.f;
  }
}

// ---------------- host ----------------
static inline size_t align256(size_t x) { return (x + 255) & ~(size_t)255; }

extern "C" void kernel_launch(void* const* d_in, const int* in_sizes, int n_in, void* d_out,
                              int out_size, void* d_ws, size_t ws_size, hipStream_t stream) {
  const float* x        = (const float*)d_in[0];
  const void*  ei       = d_in[1];
  const float* W1       = (const float*)d_in[2];
  const float* att_src1 = (const float*)d_in[3];
  const float* att_dst1 = (const float*)d_in[4];
  const float* b1       = (const float*)d_in[5];
  const float* W2       = (const float*)d_in[6];
  const float* att_src2 = (const float*)d_in[7];
  const float* att_dst2 = (const float*)d_in[8];
  const float* b2       = (const float*)d_in[9];
  float* out = (float*)d_out;

  const int C2  = in_sizes[9];       // 128
  const int H   = in_sizes[7] / C2;  // 20
  const int HC1 = in_sizes[5];       // 2560
  const int C1  = HC1 / H;           // 128
  const int G   = in_sizes[2] / HC1; // 2000
  const int Nn  = in_sizes[0] / G;   // 10000
  const int E   = in_sizes[1] / 2;   // 100000
  const int HC2 = H * C2;            // 2560
  const int Et  = E + Nn;
  const int Mpad = ((Nn + 127) / 128) * 128;
  const int K1pad = ((G + 31) / 32) * 32;  // 2048

  // workspace layout — R14-exact
  char* p = (char*)d_ws;
  size_t off = 0;
  unsigned short* hb  = (unsigned short*)(p + off); off = align256(off + (size_t)Mpad * (HC1 > HC2 ? HC1 : HC2) * 2);
  unsigned short* xb  = (unsigned short*)(p + off); off = align256(off + (size_t)Mpad * K1pad * 2);
  unsigned short* xb2 = (unsigned short*)(p + off); off = align256(off + (size_t)Mpad * HC1 * 2);
  unsigned short* W1t = (unsigned short*)(p + off); off = align256(off + (size_t)HC1 * K1pad * 2);
  unsigned short* W2t = (unsigned short*)(p + off); off = align256(off + (size_t)HC2 * HC1 * 2);
  float* a_s   = (float*)(p + off); off = align256(off + (size_t)Nn * H * 4);
  float* a_d   = (float*)(p + off); off = align256(off + (size_t)Nn * H * 4);
  float* dinv  = (float*)(p + off); off = align256(off + (size_t)Nn * H * 4);
  float* alpha = (float*)(p + off); off = align256(off + (size_t)Et * H * 4);
  int* cnt     = (int*)(p + off); off = align256(off + (size_t)Nn * 4);
  int* offs    = (int*)(p + off); off = align256(off + (size_t)(Nn + 1) * 4);
  int* fill    = (int*)(p + off); off = align256(off + (size_t)Nn * 4);
  int* srcs    = (int*)(p + off); off = align256(off + (size_t)Et * 4);
  int* flag64  = (int*)(p + off); off = align256(off + 16);
  (void)ws_size; (void)n_in; (void)out_size;

  const int TB = 256;
  // CSR build
  detect64_kernel<<<1, 1, 0, stream>>>((const unsigned int*)ei, flag64);
  init_cnt_kernel<<<(Nn + TB - 1) / TB, TB, 0, stream>>>(cnt, Nn);
  count_kernel<<<(E + TB - 1) / TB, TB, 0, stream>>>(ei, flag64, E, cnt);
  scan_kernel<<<1, 1024, 0, stream>>>(cnt, offs, Nn);
  init_self_kernel<<<(Nn + TB - 1) / TB, TB, 0, stream>>>(offs, srcs, fill, Nn);
  scatter_kernel<<<(E + TB - 1) / TB, TB, 0, stream>>>(ei, flag64, E, offs, fill, srcs);

  // packed-layout operand prep
  {
    dim3 ga(Mpad / 128, 8);
    pack_a_kernel<<<ga, 256, 0, stream>>>(x, xb, Nn, G, K1pad);
    dim3 g1(K1pad / 32, HC1 / 32);
    transpose_pack_kernel<<<g1, 256, 0, stream>>>(W1, W1t, G, HC1, K1pad);
    dim3 g2(HC1 / 32, HC2 / 32);
    transpose_pack_kernel<<<g2, 256, 0, stream>>>(W2, W2t, HC1, HC2, HC1);
  }

  // layer 1 (att-coef fused into GEMM epilogue)
  {
    dim3 grid(HC1 / 128, Mpad / 128);  // N-tile fastest
    mfma_gemm_kernel<unsigned short><<<grid, 256, 0, stream>>>(xb, W1t, hb, att_src1, att_dst1,
                                                               a_s, a_d, Nn, HC1, K1pad, H);
  }
  edge_softmax_kernel<<<(Nn * H + TB - 1) / TB, TB, 0, stream>>>(a_s, a_d, offs, srcs, alpha, dinv, Nn, H);
  aggregate1_kernel<<<Mpad / 8, 320, 0, stream>>>(hb, alpha, dinv, offs, srcs, b1, xb2, H, C1, HC1, Nn);

  // layer 2 (att-coef fused into GEMM epilogue)
  {
    dim3 grid(HC2 / 128, Mpad / 128);
    mfma_gemm_kernel<unsigned short><<<grid, 256, 0, stream>>>(xb2, W2t, hb, att_src2, att_dst2,
                                                               a_s, a_d, Nn, HC2, HC1, H);
  }
  edge_softmax_kernel<<<(Nn * H + TB - 1) / TB, TB, 0, stream>>>(a_s, a_d, offs, srcs, alpha, dinv, Nn, H);
  aggregate2_kernel<<<Nn, 256, 0, stream>>>(hb, alpha, dinv, offs, srcs, b2, out, H, C2);
}

// Round 17
// 769.079 us; speedup vs baseline: 1.1435x; 1.0193x over previous
//
#include <hip/hip_runtime.h>

#define NEG_SLOPE 0.2f

typedef __attribute__((ext_vector_type(4))) float floatx4;
typedef __attribute__((ext_vector_type(8))) short shortx8;

__device__ __forceinline__ unsigned short f2bf(float f) {
  union { float f; unsigned int u; } v;
  v.f = f;
  unsigned int r = (v.u + 0x7FFFu + ((v.u >> 16) & 1u)) >> 16;
  return (unsigned short)r;
}
__device__ __forceinline__ float bf2f(unsigned short u) {
  union { unsigned int u; float f; } v;
  v.u = (unsigned int)u << 16;
  return v.f;
}
__device__ __forceinline__ void store_out(float* p, float v) { *p = v; }
__device__ __forceinline__ void store_out(unsigned short* p, float v) { *p = f2bf(v); }

// async global->LDS, 16B per lane, LDS dest = wave-uniform base + lane*16
__device__ __forceinline__ void gload_lds16(const unsigned short* g, unsigned short* l) {
  __builtin_amdgcn_global_load_lds(
      (const __attribute__((address_space(1))) void*)(g),
      (__attribute__((address_space(3))) void*)(l), 16, 0, 0);
}

// ---------------- edge index width detection (int32 vs int64) ----------------
__device__ __forceinline__ int load_edge(const void* ei, long idx, int is64) {
  if (is64) return (int)((const long long*)ei)[idx];
  return ((const int*)ei)[idx];
}

__global__ void detect64_kernel(const unsigned int* __restrict__ p, int* __restrict__ flag) {
  int is64 = 1;
  for (int i = 0; i < 32; ++i)
    if (p[2 * i + 1] != 0u) is64 = 0;
  *flag = is64;
}

// ---------------- CSR build ----------------
__global__ void init_cnt_kernel(int* __restrict__ cnt, int n) {
  int i = blockIdx.x * blockDim.x + threadIdx.x;
  if (i < n) cnt[i] = 1;  // self-loop
}

__global__ void count_kernel(const void* __restrict__ ei, const int* __restrict__ flag, int E,
                             int* __restrict__ cnt) {
  int e = blockIdx.x * blockDim.x + threadIdx.x;
  if (e >= E) return;
  int is64 = *flag;
  int d = load_edge(ei, (long)E + e, is64);
  atomicAdd(&cnt[d], 1);
}

__global__ __launch_bounds__(1024) void scan_kernel(const int* __restrict__ cnt,
                                                    int* __restrict__ offs, int n) {
  __shared__ int partial[1024];
  int t = threadIdx.x;
  int per = (n + 1023) / 1024;
  int beg = t * per;
  int end = min(beg + per, n);
  int sum = 0;
  for (int i = beg; i < end; ++i) sum += cnt[i];
  partial[t] = sum;
  __syncthreads();
  for (int d = 1; d < 1024; d <<= 1) {
    int v = (t >= d) ? partial[t - d] : 0;
    __syncthreads();
    partial[t] += v;
    __syncthreads();
  }
  int excl = (t == 0) ? 0 : partial[t - 1];
  for (int i = beg; i < end; ++i) { offs[i] = excl; excl += cnt[i]; }
  if (t == 1023) offs[n] = partial[1023];
}

__global__ void init_self_kernel(const int* __restrict__ offs, int* __restrict__ srcs,
                                 int* __restrict__ fill, int n) {
  int i = blockIdx.x * blockDim.x + threadIdx.x;
  if (i < n) { srcs[offs[i]] = i; fill[i] = 1; }
}

__global__ void scatter_kernel(const void* __restrict__ ei, const int* __restrict__ flag, int E,
                               const int* __restrict__ offs, int* __restrict__ fill,
                               int* __restrict__ srcs) {
  int e = blockIdx.x * blockDim.x + threadIdx.x;
  if (e >= E) return;
  int is64 = *flag;
  int s = load_edge(ei, e, is64);
  int d = load_edge(ei, (long)E + e, is64);
  int pos = offs[d] + atomicAdd(&fill[d], 1);
  srcs[pos] = s;
}

// ---------------- packers: emit tile-panel-major layout [rt][kc][r128][8] ----------------
// (R5 win: +76% on GEMM. Element (row,k) lives at P[row>>7][k>>3][row&127][k&7],
// so each GEMM K-iter stages one CONTIGUOUS 8KB span per operand.)

// x f32 [M][K] -> packed bf16 [Mpad/128][Kpad/8][128][8]; rows>=M zero-filled.
__global__ __launch_bounds__(256) void pack_a_kernel(const float* __restrict__ in,
                                                     unsigned short* __restrict__ out, int M,
                                                     int K, int Kpad) {
  int rt = blockIdx.x;
  int r = threadIdx.x & 127;
  int kq = threadIdx.x >> 7;  // 0..1
  int row = rt * 128 + r;
  int nkc = Kpad >> 3;
  unsigned short* obase = out + (long)rt * Kpad * 128 + r * 8;
  const float* irow = in + (long)row * K;
  for (int kc = kq + (int)blockIdx.y * 2; kc < nkc; kc += (int)gridDim.y * 2) {
    int k = kc << 3;
    shortx8 o;
    if (row < M && k + 8 <= K && (K & 3) == 0) {
      float4 v0 = *(const float4*)(irow + k);
      float4 v1 = *(const float4*)(irow + k + 4);
      o[0] = (short)f2bf(v0.x); o[1] = (short)f2bf(v0.y);
      o[2] = (short)f2bf(v0.z); o[3] = (short)f2bf(v0.w);
      o[4] = (short)f2bf(v1.x); o[5] = (short)f2bf(v1.y);
      o[6] = (short)f2bf(v1.z); o[7] = (short)f2bf(v1.w);
    } else {
#pragma unroll
      for (int i = 0; i < 8; ++i) {
        int kk = k + i;
        float v = (row < M && kk < K) ? irow[kk] : 0.f;
        o[i] = (short)f2bf(v);
      }
    }
    *(shortx8*)(obase + (long)kc * 1024) = o;
  }
}

// W f32 [K][N] -> packed bf16 [N/128][Kpad/8][128][8] (transpose + pack).
__global__ __launch_bounds__(256) void transpose_pack_kernel(const float* __restrict__ in,
                                                             unsigned short* __restrict__ out,
                                                             int K, int N, int Kpad) {
  __shared__ float tile[32][33];
  int kb = blockIdx.x * 32;
  int nb = blockIdx.y * 32;
  int tx = threadIdx.x & 31;
  int ty = threadIdx.x >> 5;
#pragma unroll
  for (int i = 0; i < 32; i += 8) {
    int k = kb + ty + i;
    tile[ty + i][tx] = (k < K) ? in[(long)k * N + nb + tx] : 0.f;
  }
  __syncthreads();
  if (threadIdx.x < 128) {
    int nl = threadIdx.x & 31;
    int nn = nb + nl;
    int kc4 = threadIdx.x >> 5;  // 0..3
    int k0 = kc4 * 8;
    shortx8 o;
#pragma unroll
    for (int j = 0; j < 8; ++j) o[j] = (short)f2bf(tile[k0 + j][nl]);
    int kc = (kb >> 3) + kc4;
    *(shortx8*)(out + (long)(nn >> 7) * Kpad * 128 + (long)kc * 1024 + (nn & 127) * 8) = o;
  }
}

// ---------------- bf16 MFMA GEMM — packed operands, 2-DEEP prefetch + FUSED att-coef epilogue ----------------
// (R16-proven: ~185us/dispatch. K-loop/sync byte-identical to R10..R16.)
// C[M,N] = A[M,K] * Bt[N,K]^T, both operands packed [*/128][K/8][128][8].
// Per K-step: issue tile k+2's 4 DMA loads -> s_waitcnt vmcnt(8) (tiles
// k+1,k+2 stay in flight across the bare s_barrier; never vmcnt(0) mid-loop)
// -> barrier -> frags + 16 MFMA -> bare barrier.
// Tail ladder: 0x0F78=vmcnt(8) -> 0x0F74=vmcnt(4) -> 0x0F70=vmcnt(0).
// Fusion: C1=C2=128 == N-tile width -> each block's columns are EXACTLY one
// head; att-coef dot products computed in the epilogue from fp32 acc.
template <typename OT>
__global__ __launch_bounds__(256) void mfma_gemm_kernel(const unsigned short* __restrict__ A,
                                                        const unsigned short* __restrict__ Bt,
                                                        OT* __restrict__ C,
                                                        const float* __restrict__ att_s,
                                                        const float* __restrict__ att_d,
                                                        float* __restrict__ a_s,
                                                        float* __restrict__ a_d, int M, int N,
                                                        int K, int H) {
  __shared__ unsigned short As[3][4096];
  __shared__ unsigned short Bs[3][4096];
  __shared__ float red_s[2][128];
  __shared__ float red_d[2][128];

  int tid = threadIdx.x;
  int lane = tid & 63;
  int w = tid >> 6;
  int wm = w & 1, wn = w >> 1;
  int bn = blockIdx.x * 128;  // N-tile fastest
  int bm = blockIdx.y * 128;
  int quad = lane >> 4, l16 = lane & 15;

  const unsigned short* pA = A + (long)(bm >> 7) * K * 128 + tid * 8;
  const unsigned short* pB = Bt + (long)(bn >> 7) * K * 128 + tid * 8;
  unsigned short* la = &As[0][0] + w * 512;
  unsigned short* lb = &Bs[0][0] + w * 512;

  floatx4 acc[4][4];
#pragma unroll
  for (int i = 0; i < 4; ++i)
#pragma unroll
    for (int j = 0; j < 4; ++j) acc[i][j] = (floatx4){0.f, 0.f, 0.f, 0.f};

  int nk = K >> 5;
  // prologue: tile 0 -> buf0, tile 1 -> buf1
  gload_lds16(pA, la);
  gload_lds16(pA + 2048, la + 2048);
  gload_lds16(pB, lb);
  gload_lds16(pB + 2048, lb + 2048);
  if (nk > 1) {
    gload_lds16(pA + 4096, la + 4096);
    gload_lds16(pA + 4096 + 2048, la + 4096 + 2048);
    gload_lds16(pB + 4096, lb + 4096);
    gload_lds16(pB + 4096 + 2048, lb + 4096 + 2048);
  }

  int cur = 0, st = 2;
  for (int k = 0; k < nk; ++k) {
    if (k + 2 < nk) {
      const unsigned short* qA = pA + (long)(k + 2) * 4096;
      const unsigned short* qB = pB + (long)(k + 2) * 4096;
      unsigned short* da = la + st * 4096;
      unsigned short* db = lb + st * 4096;
      gload_lds16(qA, da);
      gload_lds16(qA + 2048, da + 2048);
      gload_lds16(qB, db);
      gload_lds16(qB + 2048, db + 2048);
      __builtin_amdgcn_s_waitcnt(0x0F78);  // vmcnt(8): tile k done, k+1/k+2 in flight
    } else if (k + 1 < nk) {
      __builtin_amdgcn_s_waitcnt(0x0F74);  // vmcnt(4): tile k done, k+1 in flight
    } else {
      __builtin_amdgcn_s_waitcnt(0x0F70);  // vmcnt(0): drain final tile
    }
    __builtin_amdgcn_s_barrier();  // bare barrier: in-flight DMA untouched

    shortx8 a[4], b[4];
#pragma unroll
    for (int i = 0; i < 4; ++i) {
      a[i] = *(const shortx8*)(&As[cur][(quad * 128 + wm * 64 + i * 16 + l16) * 8]);
      b[i] = *(const shortx8*)(&Bs[cur][(quad * 128 + wn * 64 + i * 16 + l16) * 8]);
    }
#pragma unroll
    for (int i = 0; i < 4; ++i)
#pragma unroll
      for (int j = 0; j < 4; ++j)
        acc[i][j] = __builtin_amdgcn_mfma_f32_16x16x32_bf16(a[i], b[j], acc[i][j], 0, 0, 0);

    // WAR guard: all reads of the buffer the next stage overwrites retired here.
    __builtin_amdgcn_s_barrier();
    cur = (cur == 2) ? 0 : cur + 1;
    st = (st == 2) ? 0 : st + 1;
  }

  // ---- fused att-coef partials (this block's 128 cols == head hh) ----
  int hh = bn >> 7;
  float att_sv[4], att_dv[4];
#pragma unroll
  for (int j = 0; j < 4; ++j) {
    int cc = wn * 64 + j * 16 + l16;
    att_sv[j] = att_s[hh * 128 + cc];
    att_dv[j] = att_d[hh * 128 + cc];
  }
#pragma unroll
  for (int i = 0; i < 4; ++i)
#pragma unroll
    for (int r2 = 0; r2 < 4; ++r2) {
      float ps = 0.f, pd = 0.f;
#pragma unroll
      for (int j = 0; j < 4; ++j) {
        float v = acc[i][j][r2];
        ps = fmaf(v, att_sv[j], ps);
        pd = fmaf(v, att_dv[j], pd);
      }
#pragma unroll
      for (int msk = 1; msk < 16; msk <<= 1) {
        ps += __shfl_xor(ps, msk, 64);
        pd += __shfl_xor(pd, msk, 64);
      }
      if (l16 == 0) {
        int row = wm * 64 + quad * 4 + i * 16 + r2;
        red_s[wn][row] = ps;
        red_d[wn][row] = pd;
      }
    }

  // epilogue: C/D layout col=lane&15, row=quad*4+reg
  int orow0 = bm + wm * 64 + quad * 4;
  int ocol0 = bn + wn * 64 + l16;
#pragma unroll
  for (int i = 0; i < 4; ++i)
#pragma unroll
    for (int j = 0; j < 4; ++j)
#pragma unroll
      for (int r2 = 0; r2 < 4; ++r2) {
        int rr = orow0 + i * 16 + r2;
        if (rr < M) store_out(&C[(long)rr * N + ocol0 + j * 16], acc[i][j][r2]);
      }

  __syncthreads();
  if (tid < 128) {
    int rr = bm + tid;
    if (rr < M) {
      a_s[(long)rr * H + hh] = red_s[0][tid] + red_s[1][tid];
      a_d[(long)rr * H + hh] = red_d[0][tid] + red_d[1][tid];
    }
  }
}

// ---------------- per-(dst,head) segment softmax over CSR — 2-pass, denom hoisted (R14) ----------------
__global__ void edge_softmax_kernel(const float* __restrict__ a_src,
                                    const float* __restrict__ a_dst,
                                    const int* __restrict__ offs, const int* __restrict__ srcs,
                                    float* __restrict__ alpha, float* __restrict__ dinv, int n,
                                    int H) {
  int idx = blockIdx.x * blockDim.x + threadIdx.x;
  if (idx >= n * H) return;
  int dstn = idx / H;
  int hh = idx - dstn * H;
  int beg = offs[dstn], end = offs[dstn + 1];
  float ad = a_dst[idx];
  float m = -1e30f;
  for (int j = beg; j < end; ++j) {
    float e = a_src[srcs[j] * H + hh] + ad;
    e = e > 0.f ? e : NEG_SLOPE * e;
    alpha[(long)j * H + hh] = e;
    m = fmaxf(m, e);
  }
  float ssum = 0.f;
  for (int j = beg; j < end; ++j) {
    float ex = __expf(alpha[(long)j * H + hh] - m);
    alpha[(long)j * H + hh] = ex;
    ssum += ex;
  }
  dinv[idx] = 1.f / ssum;
}

// ---------------- layer-1 aggregation: L2-tiled gather (16 dsts x 16 fids per block) ----------------
// R17: the R15 form strode fids across the full 5KB row -> working set = whole
// 51MB hb -> per-XCD L2 (4MB) thrash; 563MB of gathers served from L3.
// New decomposition: block = 16 consecutive dsts x 16 fids (= 128 features =
// one head at C=128). fid-chunk is the SLOW grid dim, so concurrent blocks
// share one chunk: hot data = Nn x 256B = 2.56MB -> FITS an XCD L2.
// Coalescing: per edge, the 16 fid-lanes of a dst read one contiguous 256B
// segment (lockstep j within a dst); srcs/alpha uniform across them
// (broadcast). Writes keep R15's verified contract: park acc in LDS, then
// 16 consecutive dsts x same fid = 256B contiguous packed-layout segments
// (16|128 -> never crosses a row-tile). Extra cost: edge lists + alpha
// re-walked once per chunk (~9MB total, noise).
// dst in [Nn, Mpad): beg=end, di=0 -> relu(bias) rows; GEMM guards rr<M.
__global__ __launch_bounds__(256) void aggregate1_kernel(const unsigned short* __restrict__ h,
                                                         const float* __restrict__ alpha,
                                                         const float* __restrict__ dinv,
                                                         const int* __restrict__ offs,
                                                         const int* __restrict__ srcs,
                                                         const float* __restrict__ bias,
                                                         unsigned short* __restrict__ out, int H,
                                                         int C, int HC, int Nn) {
  __shared__ unsigned short lds[16 * 136];  // [dst16][16 fids x 8 + 8 pad]
  int t = threadIdx.x;
  int cg = t & 15;        // fid within chunk
  int sub = t >> 4;       // dst within group (0..15)
  int chunk = blockIdx.y; // 16-fid chunk (= head when C==128)
  int fid = chunk * 16 + cg;
  int dst = blockIdx.x * 16 + sub;
  int hh = (fid << 3) / C;
  float bb[8];
#pragma unroll
  for (int i = 0; i < 8; ++i) bb[i] = bias[(fid << 3) + i];

  int beg = 0, end = 0;
  float di = 0.f;
  if (dst < Nn) {
    beg = offs[dst];
    end = offs[dst + 1];
    di = dinv[(long)dst * H + hh];
  }
  float acc[8];
#pragma unroll
  for (int i = 0; i < 8; ++i) acc[i] = 0.f;
  const unsigned short* hsrc = h + (fid << 3);
  for (int j = beg; j < end; ++j) {
    int s = srcs[j];
    float al = alpha[(long)j * H + hh];
    shortx8 r = *(const shortx8*)(hsrc + (long)s * HC);
#pragma unroll
    for (int i = 0; i < 8; ++i) acc[i] = fmaf(al, bf2f((unsigned short)r[i]), acc[i]);
  }
  shortx8 o;
#pragma unroll
  for (int i = 0; i < 8; ++i) o[i] = (short)f2bf(fmaxf(fmaf(acc[i], di, bb[i]), 0.f));
  *(shortx8*)&lds[sub * 136 + cg * 8] = o;
  __syncthreads();
  // write phase: sub2 = t&15 (dst), fg = t>>4 (fid) -> 256B contiguous segments
  int sub2 = t & 15;
  int fg = t >> 4;
  int dst2 = blockIdx.x * 16 + sub2;
  int fid2 = chunk * 16 + fg;
  shortx8 v = *(const shortx8*)&lds[sub2 * 136 + fg * 8];
  *(shortx8*)(out + (long)(dst2 >> 7) * HC * 128 + (long)fid2 * 1024 + (dst2 & 127) * 8) = v;
}

// ---------------- layer-2 aggregation with head-mean: vectorized, NO atomics (R12/R14-proven) ----------------
__global__ __launch_bounds__(256) void aggregate2_kernel(const unsigned short* __restrict__ h,
                                                         const float* __restrict__ alpha,
                                                         const float* __restrict__ dinv,
                                                         const int* __restrict__ offs,
                                                         const int* __restrict__ srcs,
                                                         const float* __restrict__ bias,
                                                         float* __restrict__ out, int H, int C) {
  __shared__ float smem[16 * 256];  // nHgrp x C, C<=256
  int dstn = blockIdx.x;
  int t = threadIdx.x;
  int HC = H * C;
  int nc8 = C >> 3;                 // 16 for C=128
  int c8 = t & (nc8 - 1);
  int hgrp = t >> __builtin_ctz(nc8);  // 0..nHgrp-1
  int nHgrp = 256 >> __builtin_ctz(nc8);
  int beg = offs[dstn], end = offs[dstn + 1];

  float acc[2][8];
#pragma unroll
  for (int hi = 0; hi < 2; ++hi)
#pragma unroll
    for (int i = 0; i < 8; ++i) acc[hi][i] = 0.f;

  for (int j = beg; j < end; ++j) {
    int s = srcs[j];
    const unsigned short* row = h + (long)s * HC;
    const float* al = alpha + (long)j * H;
#pragma unroll
    for (int hi = 0; hi < 2; ++hi) {
      int hh = hgrp + hi * nHgrp;
      if (hh < H) {
        float a = al[hh];
        shortx8 r = *(const shortx8*)(row + hh * C + c8 * 8);
#pragma unroll
        for (int i = 0; i < 8; ++i) acc[hi][i] = fmaf(a, bf2f((unsigned short)r[i]), acc[hi][i]);
      }
    }
  }
  // normalize per head, fold the two head-slices, park in smem[hgrp][c]
  float d0 = (hgrp < H) ? dinv[(long)dstn * H + hgrp] : 0.f;
  float d1 = (hgrp + nHgrp < H) ? dinv[(long)dstn * H + hgrp + nHgrp] : 0.f;
#pragma unroll
  for (int i = 0; i < 8; ++i)
    smem[hgrp * C + c8 * 8 + i] = acc[0][i] * d0 + acc[1][i] * d1;
  __syncthreads();
  float invH = 1.f / (float)H;
  for (int c = t; c < C; c += 256) {
    float s = 0.f;
    for (int g = 0; g < nHgrp; ++g) s += smem[g * C + c];
    float v = s * invH + bias[c];
    out[(long)dstn * C + c] = v > 0.f ? v : 0.f;
  }
}

// ---------------- host ----------------
static inline size_t align256(size_t x) { return (x + 255) & ~(size_t)255; }

extern "C" void kernel_launch(void* const* d_in, const int* in_sizes, int n_in, void* d_out,
                              int out_size, void* d_ws, size_t ws_size, hipStream_t stream) {
  const float* x        = (const float*)d_in[0];
  const void*  ei       = d_in[1];
  const float* W1       = (const float*)d_in[2];
  const float* att_src1 = (const float*)d_in[3];
  const float* att_dst1 = (const float*)d_in[4];
  const float* b1       = (const float*)d_in[5];
  const float* W2       = (const float*)d_in[6];
  const float* att_src2 = (const float*)d_in[7];
  const float* att_dst2 = (const float*)d_in[8];
  const float* b2       = (const float*)d_in[9];
  float* out = (float*)d_out;

  const int C2  = in_sizes[9];       // 128
  const int H   = in_sizes[7] / C2;  // 20
  const int HC1 = in_sizes[5];       // 2560
  const int C1  = HC1 / H;           // 128
  const int G   = in_sizes[2] / HC1; // 2000
  const int Nn  = in_sizes[0] / G;   // 10000
  const int E   = in_sizes[1] / 2;   // 100000
  const int HC2 = H * C2;            // 2560
  const int Et  = E + Nn;
  const int Mpad = ((Nn + 127) / 128) * 128;
  const int K1pad = ((G + 31) / 32) * 32;  // 2048

  // workspace layout — R14-exact
  char* p = (char*)d_ws;
  size_t off = 0;
  unsigned short* hb  = (unsigned short*)(p + off); off = align256(off + (size_t)Mpad * (HC1 > HC2 ? HC1 : HC2) * 2);
  unsigned short* xb  = (unsigned short*)(p + off); off = align256(off + (size_t)Mpad * K1pad * 2);
  unsigned short* xb2 = (unsigned short*)(p + off); off = align256(off + (size_t)Mpad * HC1 * 2);
  unsigned short* W1t = (unsigned short*)(p + off); off = align256(off + (size_t)HC1 * K1pad * 2);
  unsigned short* W2t = (unsigned short*)(p + off); off = align256(off + (size_t)HC2 * HC1 * 2);
  float* a_s   = (float*)(p + off); off = align256(off + (size_t)Nn * H * 4);
  float* a_d   = (float*)(p + off); off = align256(off + (size_t)Nn * H * 4);
  float* dinv  = (float*)(p + off); off = align256(off + (size_t)Nn * H * 4);
  float* alpha = (float*)(p + off); off = align256(off + (size_t)Et * H * 4);
  int* cnt     = (int*)(p + off); off = align256(off + (size_t)Nn * 4);
  int* offs    = (int*)(p + off); off = align256(off + (size_t)(Nn + 1) * 4);
  int* fill    = (int*)(p + off); off = align256(off + (size_t)Nn * 4);
  int* srcs    = (int*)(p + off); off = align256(off + (size_t)Et * 4);
  int* flag64  = (int*)(p + off); off = align256(off + 16);
  (void)ws_size; (void)n_in; (void)out_size;

  const int TB = 256;
  // CSR build
  detect64_kernel<<<1, 1, 0, stream>>>((const unsigned int*)ei, flag64);
  init_cnt_kernel<<<(Nn + TB - 1) / TB, TB, 0, stream>>>(cnt, Nn);
  count_kernel<<<(E + TB - 1) / TB, TB, 0, stream>>>(ei, flag64, E, cnt);
  scan_kernel<<<1, 1024, 0, stream>>>(cnt, offs, Nn);
  init_self_kernel<<<(Nn + TB - 1) / TB, TB, 0, stream>>>(offs, srcs, fill, Nn);
  scatter_kernel<<<(E + TB - 1) / TB, TB, 0, stream>>>(ei, flag64, E, offs, fill, srcs);

  // packed-layout operand prep
  {
    dim3 ga(Mpad / 128, 8);
    pack_a_kernel<<<ga, 256, 0, stream>>>(x, xb, Nn, G, K1pad);
    dim3 g1(K1pad / 32, HC1 / 32);
    transpose_pack_kernel<<<g1, 256, 0, stream>>>(W1, W1t, G, HC1, K1pad);
    dim3 g2(HC1 / 32, HC2 / 32);
    transpose_pack_kernel<<<g2, 256, 0, stream>>>(W2, W2t, HC1, HC2, HC1);
  }

  // layer 1 (att-coef fused into GEMM epilogue)
  {
    dim3 grid(HC1 / 128, Mpad / 128);  // N-tile fastest
    mfma_gemm_kernel<unsigned short><<<grid, 256, 0, stream>>>(xb, W1t, hb, att_src1, att_dst1,
                                                               a_s, a_d, Nn, HC1, K1pad, H);
  }
  edge_softmax_kernel<<<(Nn * H + TB - 1) / TB, TB, 0, stream>>>(a_s, a_d, offs, srcs, alpha, dinv, Nn, H);
  {
    dim3 ga1(Mpad / 16, HC1 / 128);  // dst-groups fast, fid-chunks slow
    aggregate1_kernel<<<ga1, 256, 0, stream>>>(hb, alpha, dinv, offs, srcs, b1, xb2, H, C1, HC1, Nn);
  }

  // layer 2 (att-coef fused into GEMM epilogue)
  {
    dim3 grid(HC2 / 128, Mpad / 128);
    mfma_gemm_kernel<unsigned short><<<grid, 256, 0, stream>>>(xb2, W2t, hb, att_src2, att_dst2,
                                                               a_s, a_d, Nn, HC2, HC1, H);
  }
  edge_softmax_kernel<<<(Nn * H + TB - 1) / TB, TB, 0, stream>>>(a_s, a_d, offs, srcs, alpha, dinv, Nn, H);
  aggregate2_kernel<<<Nn, 256, 0, stream>>>(hb, alpha, dinv, offs, srcs, b2, out, H, C2);
}